// Round 11
// baseline (1190.183 us; speedup 1.0000x reference)
//
#include <hip/hip_runtime.h>
#include <hip/hip_bf16.h>
#include <math.h>

typedef __hip_bfloat16 bf16;
typedef __attribute__((ext_vector_type(8))) short short8;
typedef __attribute__((ext_vector_type(4))) short short4v;
typedef __attribute__((ext_vector_type(4))) float float4v;

#define ACT_NONE 0
#define ACT_RELU 1
#define ACT_GELU 2

__device__ __forceinline__ float b2f(bf16 v){ return __bfloat162float(v); }
__device__ __forceinline__ bf16  f2b(float f){ return __float2bfloat16(f); }
__device__ __forceinline__ short f2bs(float f){ bf16 h = __float2bfloat16(f); return *reinterpret_cast<short*>(&h); }
__device__ __forceinline__ float bs2f(short s){ return __uint_as_float(((unsigned)(unsigned short)s) << 16); }
__device__ __forceinline__ void rotc(float& tr, float& ti, float cr, float ci){
    float t = tr*cr - ti*ci; ti = tr*ci + ti*cr; tr = t;
}

struct GK3 { float k[3][41]; int ks[3]; };

// ---------------- merged init: conv_ps (bx<4096) + weight packing ----------------
__global__ __launch_bounds__(256) void init_k(const float* __restrict__ lrms,
        const float* __restrict__ wps, float* __restrict__ up,
        const float* __restrict__ mw_in, const float* __restrict__ mw_h,
        const float* __restrict__ mw_out, const float* __restrict__ hor_w2,
        const float* __restrict__ ref_in, const float* __restrict__ ref_b1,
        const float* __restrict__ ref_b2, const float* __restrict__ ref_out,
        const float* __restrict__ l2l, const float* __restrict__ l2g,
        const float* __restrict__ g2l,
        short* __restrict__ wp, short* __restrict__ wc){
    int tid = threadIdx.x, bx = blockIdx.x;
    if (bx < 4096) {
        int y = bx & 255, c = (bx >> 8) & 3, b = bx >> 10;
        int x = tid;
        int h = y >> 2, r1 = y & 3, ww = x >> 2, r2 = x & 3;
        int oc = c*16 + r1*4 + r2;
        float acc = 0.f;
        for (int ic = 0; ic < 4; ++ic) {
            const float* base = lrms + ((b*4 + ic) << 12);
            const float* wb = wps + (oc*4 + ic)*9;
            #pragma unroll
            for (int ky = 0; ky < 3; ++ky) {
                int hh = h + ky - 1; if (hh < 0 || hh > 63) continue;
                #pragma unroll
                for (int kx = 0; kx < 3; ++kx) {
                    int cc = ww + kx - 1; if (cc < 0 || cc > 63) continue;
                    acc += base[(hh<<6) + cc] * wb[ky*3 + kx];
                }
            }
        }
        up[(((size_t)(b*4 + c)) << 16) + (y<<8) + x] = acc;
        return;
    }
    int idx = (bx - 4096)*256 + tid;
    const int S0 = 40960, SH = 65536;
    const int TOTM = S0 + 3*SH + 4096;
    const int TOTC = 45*2560;
    if (idx < TOTM) {
        float val;
        if (idx < S0) {
            int j = idx & 7, l = (idx>>3) & 63, nt = (idx>>9) & 15, kt = idx >> 13;
            int k = kt*32 + (l>>4)*8 + j;
            int n = nt*16 + (l&15);
            val = (k < 148) ? mw_in[k*256 + n] : 0.f;
        } else if (idx < S0 + 3*SH) {
            int i2 = idx - S0;
            int L = i2 >> 16, r = i2 & 65535;
            int j = r & 7, l = (r>>3) & 63, nt = (r>>9) & 15, kt = r >> 13;
            int k = kt*32 + (l>>4)*8 + j;
            int n = nt*16 + (l&15);
            val = mw_h[L*65536 + k*256 + n];
        } else {
            int i3 = idx - S0 - 3*SH;
            int j = i3 & 7, l = (i3>>3) & 63, kt = i3 >> 9;
            int k = kt*32 + (l>>4)*8 + j;
            int oc = l & 15;
            val = mw_out[k*16 + oc];
        }
        wp[idx] = f2bs(val);
        return;
    }
    int idx2 = idx - TOTM;
    if (idx2 >= TOTC) return;
    int set = idx2 / 2560, r = idx2 % 2560;
    int j = r & 7, l = (r>>3) & 63, kt = r >> 9;
    int k = kt*32 + ((l>>4)&3)*8 + j;
    int n = l & 15;
    int g = set / 3, br = set % 3;
    float v = 0.f;
    if (k < 144) {
        int tap = k >> 4, ic = k & 15;
        if (g == 10 || g == 11) {
            int wi = 2*br + (g-10);
            if (n < 8) v = (ic < 8) ? l2g[((wi*8 + n)*8 + ic)*9 + tap] : 0.f;
            else {
                int o = n - 8;
                v = (ic < 8) ? l2l[((wi*8 + o)*8 + ic)*9 + tap]
                             : g2l[((wi*8 + o)*8 + (ic-8))*9 + tap];
            }
        } else {
            int widx = (n*16 + ic)*9 + tap;
            const float* src;
            if (g == 0)       src = hor_w2 + br*2304;
            else if (g <= 3)  src = ref_in + (3*br + (g-1))*2304;
            else if (g <= 6)  src = ref_b1 + (3*br + (g-4))*2304;
            else if (g <= 9)  src = ref_b2 + (3*br + (g-7))*2304;
            else              src = ref_out + (3*br + (g-12))*2304;
            v = src[widx];
        }
    }
    wc[idx2] = f2bs(v);
}

// ---------------- fused gaussian highpass -------------------------------------
__global__ __launch_bounds__(256) void gauss_hp_k(const float* __restrict__ pan,
                                                  const float* __restrict__ lrms_up,
                                                  bf16* __restrict__ feat2, GK3 g){
    int tid = threadIdx.x, bx = blockIdx.x;
    int y = bx & 255, b = (bx >> 8) & 3, src = (bx >> 10) & 1, br = bx >> 11;
    int ks = g.ks[br], p = ks >> 1;
    const float* gk = g.k[br];
    const float* s = src ? (lrms_up + (size_t)b*4*65536) : (pan + (size_t)b*65536);
    __shared__ float vext[296];
    for (int i = tid; i < 296; i += 256) {
        int xe = i - 20; int xr = xe < 0 ? -xe : (xe > 255 ? 510 - xe : xe);
        float acc = 0.f;
        for (int t = 0; t < ks; ++t) {
            int yy = y - p + t; yy = yy < 0 ? -yy : (yy > 255 ? 510 - yy : yy);
            acc += gk[t] * s[(yy<<8) + xr];
        }
        vext[i] = acc;
    }
    __syncthreads();
    int x = tid;
    float acc = 0.f;
    for (int t = 0; t < ks; ++t) acc += gk[t] * vext[x - p + t + 20];
    float o = s[(y<<8) + x];
    feat2[(((size_t)((br*4 + b)*2 + src)) << 16) + (y<<8) + x] = f2b(o - acc);
}

// ---------------- scalar 3x3 conv (hornet conv1, Cin=2) -------------------------
__global__ __launch_bounds__(256) void convA_k(const bf16* __restrict__ in, int inCper, int Cin,
                                               const float* __restrict__ wbase, int wbrstride, int wocstride,
                                               bf16* __restrict__ out, int act){
    int tid = threadIdx.x, bx = blockIdx.x;
    int y = bx & 255, b = (bx >> 8) & 3, br = bx >> 10;
    const float* w = wbase + (size_t)br * wbrstride;
    int x = tid;
    float acc[16];
    #pragma unroll
    for (int oc = 0; oc < 16; ++oc) acc[oc] = 0.f;
    for (int ic = 0; ic < Cin; ++ic) {
        const bf16* base = in + ((size_t)((br*4 + b)*inCper + ic) << 16);
        const float* wic = w + ic*9;
        #pragma unroll
        for (int ky = 0; ky < 3; ++ky) {
            int yy = y + ky - 1; if (yy < 0 || yy > 255) continue;
            const bf16* rowp = base + (yy<<8);
            float v0 = (x > 0)   ? b2f(rowp[x-1]) : 0.f;
            float v1 = b2f(rowp[x]);
            float v2 = (x < 255) ? b2f(rowp[x+1]) : 0.f;
            const float* wr = wic + ky*3;
            #pragma unroll
            for (int oc = 0; oc < 16; ++oc) {
                const float* wo = wr + oc*wocstride;
                acc[oc] = fmaf(wo[0], v0, fmaf(wo[1], v1, fmaf(wo[2], v2, acc[oc])));
            }
        }
    }
    #pragma unroll
    for (int oc = 0; oc < 16; ++oc) {
        float a = acc[oc];
        if (act == ACT_RELU) a = fmaxf(a, 0.f);
        else if (act == ACT_GELU) {
            float u = 0.7978845608028654f * (a + 0.044715f*a*a*a);
            a = 0.5f * a * (1.f + tanhf(u));
        }
        out[((size_t)((br*4 + b)*16 + oc) << 16) + (y<<8) + x] = f2b(a);
    }
}

// ---------------- MFMA 3x3 conv, 4 output rows per block ------------------------
__global__ __launch_bounds__(256) void convM_k(const bf16* __restrict__ in,
        const short* __restrict__ wgroup,
        bf16* __restrict__ out, int act, float* __restrict__ means){
    __shared__ short sIn[6*258*20];
    __shared__ float sm[4][16];
    int tid = threadIdx.x, bx = blockIdx.x;
    int y0 = (bx & 63) << 2, b = (bx >> 6) & 3, br = bx >> 8;
    size_t pbase = (size_t)((br*4 + b)*16) << 16;
    if (tid < 192) {
        int r = tid >> 5, side = (tid >> 4) & 1, ic = tid & 15;
        sIn[(r*258 + (side ? 257 : 0))*20 + ic] = 0;
    }
    {
        int g = tid >> 5, tl = tid & 31, x0 = tl << 3, ic0 = g*2;
        for (int r = 0; r < 6; ++r) {
            int yy = y0 - 1 + r;
            short8 lo = {0,0,0,0,0,0,0,0}, hi = {0,0,0,0,0,0,0,0};
            if (yy >= 0 && yy <= 255) {
                lo = *(const short8*)&in[pbase + ((size_t)ic0<<16) + (yy<<8) + x0];
                hi = *(const short8*)&in[pbase + ((size_t)(ic0+1)<<16) + (yy<<8) + x0];
            }
            #pragma unroll
            for (int t = 0; t < 8; ++t) {
                int v = (int)(unsigned short)lo[t] | ((int)(unsigned short)hi[t] << 16);
                *(int*)&sIn[(r*258 + x0 + t + 1)*20 + ic0] = v;
            }
        }
    }
    __syncthreads();
    int l = tid & 63, w = tid >> 6, m_l = l & 15, q = l >> 4;
    const short* wp = wgroup + br*2560;
    short8 bfr[5];
    #pragma unroll
    for (int kt = 0; kt < 5; ++kt)
        bfr[kt] = *(const short8*)(wp + (kt*64 + l)*8);
    float4v acc[16];
    #pragma unroll
    for (int j = 0; j < 16; ++j) acc[j] = (float4v){0.f,0.f,0.f,0.f};
    #pragma unroll
    for (int kt = 0; kt < 5; ++kt) {
        int k0 = kt*32 + q*8;
        bool pad = (k0 >= 144);
        int tap = pad ? 0 : (k0 >> 4);
        int icb = k0 & 15;
        int ky = tap/3, kx = tap - ky*3;
        int rbase = (w + ky)*258 + kx;
        #pragma unroll
        for (int j = 0; j < 16; ++j) {
            int x = j*16 + m_l;
            const short* ap = &sIn[(rbase + x)*20 + icb];
            short4v alo = *(const short4v*)ap;
            short4v ahi = *(const short4v*)(ap + 4);
            short8 a;
            #pragma unroll
            for (int t = 0; t < 4; ++t) { a[t] = pad ? (short)0 : alo[t]; a[t+4] = pad ? (short)0 : ahi[t]; }
            acc[j] = __builtin_amdgcn_mfma_f32_16x16x32_bf16(a, bfr[kt], acc[j], 0, 0, 0);
        }
    }
    if (means) {
        float s = 0.f;
        #pragma unroll
        for (int j = 0; j < 16; ++j)
            #pragma unroll
            for (int r = 0; r < 4; ++r) s += acc[j][r];
        s += __shfl_xor(s, 16, 64);
        s += __shfl_xor(s, 32, 64);
        if (l < 16) sm[w][l] = s;
        __syncthreads();
        if (tid < 16) atomicAdd(&means[br*64 + b*16 + tid],
                                sm[0][tid] + sm[1][tid] + sm[2][tid] + sm[3][tid]);
    }
    int yrow = y0 + w;
    #pragma unroll
    for (int j = 0; j < 16; ++j) {
        short4v pk;
        #pragma unroll
        for (int r = 0; r < 4; ++r) {
            float a = acc[j][r];
            if (act == ACT_RELU) a = fmaxf(a, 0.f);
            else if (act == ACT_GELU) {
                float u = 0.7978845608028654f * (a + 0.044715f*a*a*a);
                a = 0.5f * a * (1.f + tanhf(u));
            }
            pk[r] = f2bs(a);
        }
        *(short4v*)&out[pbase + ((size_t)m_l << 16) + (yrow<<8) + j*16 + q*4] = pk;
    }
}

// ---------------- MFMA refine-out conv: ca computed inline, + fuse 1x1 ----------
__global__ __launch_bounds__(256) void convOutM_k(const bf16* __restrict__ Y, const bf16* __restrict__ BDY,
        const float* __restrict__ means, const float* __restrict__ ca1, const float* __restrict__ ca2,
        const short* __restrict__ wgroup,
        const float* __restrict__ wfuse, int step,
        bf16* __restrict__ F, bf16* __restrict__ fusedCat){
    __shared__ short sIn[6*258*20];
    __shared__ float sCav[16];
    int tid = threadIdx.x, bx = blockIdx.x;
    int y0 = (bx & 63) << 2, b = (bx >> 6) & 3, br = bx >> 8;
    size_t pbase = (size_t)((br*4 + b)*16) << 16;
    if (tid < 192) {
        int r = tid >> 5, side = (tid >> 4) & 1, ic = tid & 15;
        sIn[(r*258 + (side ? 257 : 0))*20 + ic] = 0;
    }
    if (tid < 16) {
        int ri = 3*br + step;
        const float* w1 = ca1 + ri*64; const float* w2 = ca2 + ri*64;
        float hid[4];
        #pragma unroll
        for (int c2 = 0; c2 < 4; ++c2) {
            float a = 0.f;
            for (int c = 0; c < 16; ++c) a += w1[c2*16 + c] * (means[br*64 + b*16 + c] * (1.f/65536.f));
            hid[c2] = fmaxf(a, 0.f);
        }
        float v = 0.f;
        #pragma unroll
        for (int c2 = 0; c2 < 4; ++c2) v += w2[tid*4 + c2] * hid[c2];
        sCav[tid] = 1.f / (1.f + expf(-v));
    }
    __syncthreads();
    {
        int g = tid >> 5, tl = tid & 31, x0 = tl << 3, ic0 = g*2;
        float c0 = sCav[ic0];
        float c1 = sCav[ic0 + 1];
        for (int r = 0; r < 6; ++r) {
            int yy = y0 - 1 + r;
            short8 ylo = {0,0,0,0,0,0,0,0}, yhi = ylo, dlo = ylo, dhi = ylo;
            if (yy >= 0 && yy <= 255) {
                size_t o0 = pbase + ((size_t)ic0<<16) + (yy<<8) + x0;
                size_t o1 = pbase + ((size_t)(ic0+1)<<16) + (yy<<8) + x0;
                ylo = *(const short8*)&Y[o0];   yhi = *(const short8*)&Y[o1];
                dlo = *(const short8*)&BDY[o0]; dhi = *(const short8*)&BDY[o1];
            }
            #pragma unroll
            for (int t = 0; t < 8; ++t) {
                short s0 = f2bs(fmaf(bs2f(dlo[t]), c0, bs2f(ylo[t])));
                short s1 = f2bs(fmaf(bs2f(dhi[t]), c1, bs2f(yhi[t])));
                int v = (int)(unsigned short)s0 | ((int)(unsigned short)s1 << 16);
                *(int*)&sIn[(r*258 + x0 + t + 1)*20 + ic0] = v;
            }
        }
    }
    __syncthreads();
    int l = tid & 63, w = tid >> 6, m_l = l & 15, q = l >> 4;
    const short* wp = wgroup + br*2560;
    short8 bfr[5];
    #pragma unroll
    for (int kt = 0; kt < 5; ++kt)
        bfr[kt] = *(const short8*)(wp + (kt*64 + l)*8);
    float4v acc[16];
    #pragma unroll
    for (int j = 0; j < 16; ++j) acc[j] = (float4v){0.f,0.f,0.f,0.f};
    #pragma unroll
    for (int kt = 0; kt < 5; ++kt) {
        int k0 = kt*32 + q*8;
        bool pad = (k0 >= 144);
        int tap = pad ? 0 : (k0 >> 4);
        int icb = k0 & 15;
        int ky = tap/3, kx = tap - ky*3;
        int rbase = (w + ky)*258 + kx;
        #pragma unroll
        for (int j = 0; j < 16; ++j) {
            int x = j*16 + m_l;
            const short* ap = &sIn[(rbase + x)*20 + icb];
            short4v alo = *(const short4v*)ap;
            short4v ahi = *(const short4v*)(ap + 4);
            short8 a;
            #pragma unroll
            for (int t = 0; t < 4; ++t) { a[t] = pad ? (short)0 : alo[t]; a[t+4] = pad ? (short)0 : ahi[t]; }
            acc[j] = __builtin_amdgcn_mfma_f32_16x16x32_bf16(a, bfr[kt], acc[j], 0, 0, 0);
        }
    }
    int yrow = y0 + w;
    #pragma unroll
    for (int j = 0; j < 16; ++j) {
        short4v pk;
        #pragma unroll
        for (int r = 0; r < 4; ++r) pk[r] = f2bs(acc[j][r]);
        *(short4v*)&F[pbase + ((size_t)m_l << 16) + (yrow<<8) + j*16 + q*4] = pk;
    }
    __syncthreads();            // everyone done reading sIn; reuse as sF
    short* sF = sIn + w*4096;   // per-wave 256px x 16oc
    #pragma unroll
    for (int j = 0; j < 16; ++j)
        #pragma unroll
        for (int r = 0; r < 4; ++r)
            sF[(j*16 + q*4 + r)*16 + m_l] = f2bs(acc[j][r]);
    const float* wf = wfuse + br*768 + step*16;   // wf[oc2*48 + oc]
    short8 b2;
    #pragma unroll
    for (int jj = 0; jj < 8; ++jj) {
        int k = q*8 + jj;
        b2[jj] = (k < 16) ? f2bs(wf[m_l*48 + k]) : (short)0;
    }
    #pragma unroll
    for (int mt = 0; mt < 16; ++mt) {
        short8 a2 = {0,0,0,0,0,0,0,0};
        if (q < 2) a2 = *(const short8*)&sF[(mt*16 + m_l)*16 + q*8];
        float4v d2 = (float4v){0.f,0.f,0.f,0.f};
        d2 = __builtin_amdgcn_mfma_f32_16x16x32_bf16(a2, b2, d2, 0, 0, 0);
        size_t fidx = ((size_t)(b*48 + br*16 + m_l) << 16) + (yrow<<8) + mt*16 + q*4;
        short4v pk;
        if (step == 0) {
            #pragma unroll
            for (int r = 0; r < 4; ++r) pk[r] = f2bs(d2[r]);
        } else {
            short4v old = *(const short4v*)&fusedCat[fidx];
            #pragma unroll
            for (int r = 0; r < 4; ++r) pk[r] = f2bs(bs2f(old[r]) + d2[r]);
        }
        *(short4v*)&fusedCat[fidx] = pk;
    }
}

// ---------------- radix-16 rfft along W, TRANSPOSED out, barrier-batched --------
__global__ __launch_bounds__(256) void rfft_wT_k(const bf16* __restrict__ F,
                                                 bf16* __restrict__ ore, bf16* __restrict__ oim){
    __shared__ float ubuf[4386];                   // rows[16][256] then Tr/Ti[129][17]
    extern __shared__ float2 Acx[];                // [16][256] dynamic 32KB
    float (*rows)[256] = (float(*)[256])ubuf;
    float (*Tr)[17] = (float(*)[17])ubuf;
    float (*Ti)[17] = (float(*)[17])(ubuf + 129*17);
    int tid = threadIdx.x, bx = blockIdx.x;
    int t = bx & 15, c = (bx >> 4) & 7, b = (bx >> 7) & 3, br = bx >> 9;
    int y0 = t << 4;
    size_t plane = (size_t)((br*4 + b)*16 + 8 + c) << 16;
    #pragma unroll
    for (int r = 0; r < 16; ++r)
        rows[r][tid] = b2f(F[plane + ((size_t)(y0 + r) << 8) + tid]);
    __syncthreads();
    int n1 = tid >> 4, k1 = tid & 15;
    float a1 = -6.283185307179586f * (float)k1 / 16.f;
    float c1, s1; __sincosf(a1, &s1, &c1);
    for (int r = 0; r < 16; ++r) {
        float twr = 1.f, twi = 0.f, ar = 0.f, ai = 0.f;
        #pragma unroll
        for (int n2 = 0; n2 < 16; ++n2) {
            float xr = rows[r][n1 + (n2<<4)];
            ar = fmaf(xr, twr, ar); ai = fmaf(xr, twi, ai);
            rotc(twr, twi, c1, s1);
        }
        Acx[r*256 + tid] = make_float2(ar, ai);
    }
    __syncthreads();
    if (tid < 129) {
        int kk1 = tid & 15;
        float a2 = -6.283185307179586f * (float)tid / 256.f;
        float c2v, s2v; __sincosf(a2, &s2v, &c2v);
        for (int r = 0; r < 16; ++r) {
            float t2r = 1.f, t2i = 0.f, re = 0.f, im = 0.f;
            #pragma unroll
            for (int m = 0; m < 16; ++m) {
                float2 A = Acx[r*256 + (m<<4) + kk1];
                re += A.x*t2r - A.y*t2i; im += A.y*t2r + A.x*t2i;
                rotc(t2r, t2i, c2v, s2v);
            }
            Tr[tid][r] = re * 0.0625f; Ti[tid][r] = im * 0.0625f;
        }
    }
    __syncthreads();
    size_t obase = ((size_t)(((br*4 + b)*8 + c)*129)) * 256 + y0;
    for (int idx = tid; idx < 129*16; idx += 256) {
        int k = idx >> 4, ty = idx & 15;
        ore[obase + (size_t)k*256 + ty] = f2b(Tr[k][ty]);
        oim[obase + (size_t)k*256 + ty] = f2b(Ti[k][ty]);
    }
}

// ---------------- FUSED fft_h fwd -> spec -> fft_h inv, barrier-batched ----------
__global__ __launch_bounds__(256) void fftspec_hT_k(const bf16* __restrict__ re0, const bf16* __restrict__ im0,
                                                    const float* __restrict__ wspec, int step,
                                                    bf16* __restrict__ re1, bf16* __restrict__ im1){
    __shared__ float2 Fc[8][256];
    __shared__ float2 Sc[8][256];
    int tid = threadIdx.x, bx = blockIdx.x;
    int k = bx % 129; int r2 = bx / 129; int b = r2 & 3, br = r2 >> 2;
    size_t cb = (size_t)((br*4 + b)*8) * 33024 + (size_t)k * 256;
    int n1 = tid >> 4, k1 = tid & 15;
    float a1 = -6.283185307179586f * (float)k1 / 16.f;
    float c1, s1; __sincosf(a1, &s1, &c1);
    float a2 = -6.283185307179586f * (float)tid / 256.f;
    float c2v, s2v; __sincosf(a2, &s2v, &c2v);
    #pragma unroll
    for (int c = 0; c < 8; ++c) {
        size_t base = cb + (size_t)c*33024 + tid;
        Fc[c][tid] = make_float2(b2f(re0[base]), b2f(im0[base]));
    }
    __syncthreads();
    // forward stage 1 (all channels)
    for (int c = 0; c < 8; ++c) {
        float twr = 1.f, twi = 0.f, ar = 0.f, ai = 0.f;
        #pragma unroll
        for (int n2 = 0; n2 < 16; ++n2) {
            float2 x = Fc[c][n1 + (n2<<4)];
            ar += x.x*twr - x.y*twi; ai += x.y*twr + x.x*twi;
            rotc(twr, twi, c1, s1);
        }
        Sc[c][tid] = make_float2(ar, ai);
    }
    __syncthreads();
    // forward stage 2 (all channels), scaled
    for (int c = 0; c < 8; ++c) {
        float t2r = 1.f, t2i = 0.f, rr = 0.f, ii = 0.f;
        #pragma unroll
        for (int m = 0; m < 16; ++m) {
            float2 A = Sc[c][(m<<4) + k1];
            rr += A.x*t2r - A.y*t2i; ii += A.y*t2r + A.x*t2i;
            rotc(t2r, t2i, c2v, s2v);
        }
        Fc[c][tid] = make_float2(rr * 0.0625f, ii * 0.0625f);
    }
    __syncthreads();
    // spectral 1x1 + relu
    {
        const float* wl = wspec + (2*br + step)*256;
        float outv[16];
        #pragma unroll
        for (int oc = 0; oc < 16; ++oc) {
            float acc = 0.f;
            #pragma unroll
            for (int ic = 0; ic < 8; ++ic) {
                float2 gv = Fc[ic][tid];
                acc += gv.x * wl[oc*16 + ic] + gv.y * wl[oc*16 + 8 + ic];
            }
            outv[oc] = fmaxf(acc, 0.f);
        }
        __syncthreads();
        #pragma unroll
        for (int oc = 0; oc < 8; ++oc) Sc[oc][tid] = make_float2(outv[oc], outv[oc+8]);
    }
    __syncthreads();
    // inverse stage 1
    for (int c = 0; c < 8; ++c) {
        float twr = 1.f, twi = 0.f, ar = 0.f, ai = 0.f;
        #pragma unroll
        for (int n2 = 0; n2 < 16; ++n2) {
            float2 x = Sc[c][n1 + (n2<<4)];
            ar += x.x*twr + x.y*twi;
            ai += x.y*twr - x.x*twi;
            rotc(twr, twi, c1, s1);
        }
        Fc[c][tid] = make_float2(ar, ai);
    }
    __syncthreads();
    // inverse stage 2 -> global
    for (int c = 0; c < 8; ++c) {
        float t2r = 1.f, t2i = 0.f, rr = 0.f, ii = 0.f;
        #pragma unroll
        for (int m = 0; m < 16; ++m) {
            float2 A = Fc[c][(m<<4) + k1];
            rr += A.x*t2r + A.y*t2i;
            ii += A.y*t2r - A.x*t2i;
            rotc(t2r, t2i, c2v, s2v);
        }
        size_t base = cb + (size_t)c*33024 + tid;
        re1[base] = f2b(rr * 0.0625f);
        im1[base] = f2b(ii * 0.0625f);
    }
}

// ---------------- c2r irfft along W from [k][y], barrier-batched -----------------
__global__ __launch_bounds__(256) void irfft_wT_k(const bf16* __restrict__ re1, const bf16* __restrict__ im1,
                                                  bf16* __restrict__ A){
    __shared__ float2 Ecx[16][258];                // [ty][i], Hermitian-extended
    extern __shared__ float2 Acx[];                // [16][256] dynamic 32KB
    int tid = threadIdx.x, bx = blockIdx.x;
    int t = bx & 15, c = (bx >> 4) & 7, b = (bx >> 7) & 3, br = bx >> 9;
    int y0 = t << 4;
    size_t ibase = ((size_t)(((br*4 + b)*8 + c)*129)) * 256 + y0;
    for (int idx = tid; idx < 16*256; idx += 256) {
        int i = idx >> 4, ty = idx & 15;
        int k = (i < 129) ? i : 256 - i;
        float re = b2f(re1[ibase + (size_t)k*256 + ty]);
        float im = (k == 0 || k == 128) ? 0.f : b2f(im1[ibase + (size_t)k*256 + ty]);
        if (i >= 129) im = -im;
        Ecx[ty][i] = make_float2(re, im);
    }
    __syncthreads();
    int n1 = tid >> 4, k1 = tid & 15;
    float a1 = 6.283185307179586f * (float)k1 / 16.f;
    float c1, s1; __sincosf(a1, &s1, &c1);
    for (int ty = 0; ty < 16; ++ty) {
        float twr = 1.f, twi = 0.f, ar = 0.f, ai = 0.f;
        #pragma unroll
        for (int n2 = 0; n2 < 16; ++n2) {
            float2 x = Ecx[ty][n1 + (n2<<4)];
            ar += x.x*twr - x.y*twi; ai += x.y*twr + x.x*twi;
            rotc(twr, twi, c1, s1);
        }
        Acx[ty*256 + tid] = make_float2(ar, ai);
    }
    __syncthreads();
    float a2 = 6.283185307179586f * (float)tid / 256.f;
    float c2v, s2v; __sincosf(a2, &s2v, &c2v);
    size_t plane = (size_t)((br*4 + b)*16 + c) << 16;
    for (int ty = 0; ty < 16; ++ty) {
        float t2r = 1.f, t2i = 0.f, racc = 0.f;
        #pragma unroll
        for (int m = 0; m < 16; ++m) {
            float2 Av = Acx[ty*256 + (m<<4) + k1];
            racc += Av.x*t2r - Av.y*t2i;
            rotc(t2r, t2i, c2v, s2v);
        }
        size_t o = plane + ((size_t)(y0 + ty) << 8) + tid;
        A[o] = f2b(b2f(A[o]) + racc * 0.0625f);
    }
}

// ---------------- fuse 1x1 (48->16), interleaved feat_all out --------------------
__global__ __launch_bounds__(256) void fuse1x1_k(const bf16* __restrict__ fc, const float* __restrict__ wl,
                                                 bf16* __restrict__ feat_all){
    int tid = threadIdx.x, bx = blockIdx.x;
    int pt = bx & 255, b = bx >> 8;
    int p = (pt << 8) + tid;
    float acc[16];
    #pragma unroll
    for (int oc = 0; oc < 16; ++oc) acc[oc] = 0.f;
    for (int ic = 0; ic < 48; ++ic) {
        float v = b2f(fc[((size_t)(b*48 + ic) << 16) + p]);
        #pragma unroll
        for (int oc = 0; oc < 16; ++oc) acc[oc] = fmaf(wl[oc*48 + ic], v, acc[oc]);
    }
    size_t obase = (((size_t)b << 16) + p) << 4;
    #pragma unroll
    for (int h = 0; h < 2; ++h) {
        short8 pk;
        #pragma unroll
        for (int e = 0; e < 8; ++e) pk[e] = f2bs(acc[h*8 + e]);
        *(short8*)&feat_all[obase + h*8] = pk;
    }
}

// ---------------- LIIF MLP via MFMA (center), 256 thr / 64 px, prefetch ----------
__global__ __launch_bounds__(256) void mlp_mfma_k(const short* __restrict__ feat,
        const short* __restrict__ wp,
        const float* __restrict__ b_in, const float* __restrict__ b_h,
        const float* __restrict__ b_out,
        float* __restrict__ fo){
    extern __shared__ short act_s[];   // 64 rows x 264 shorts
    int tid = threadIdx.x, bx = blockIdx.x;
    long P0 = (long)bx * 64;
    for (int idx = tid; idx < 64*160; idx += 256) {
        int pp = idx / 160, j = idx - pp*160;
        long P = P0 + pp;
        int bb = (int)(P >> 16), pim = (int)(P & 65535);
        int s0 = pim >> 8, s1 = pim & 255;
        short v = 0;
        if (j < 144) {
            int iy = j/48, ix = (j>>4)%3, c2 = j&15;
            int yy = s0 + iy - 1, xx = s1 + ix - 1;
            if (yy >= 0 && yy < 256 && xx >= 0 && xx < 256)
                v = feat[((((long)bb << 16) + (yy<<8) + xx) << 4) + c2];
        } else if (j == 146 || j == 147) v = 0x4000;
        act_s[pp*264 + j] = v;
    }
    __syncthreads();

    int l = tid & 63, w = tid >> 6;
    int m_l = l & 15, q = l >> 4;
    int ntb = w*4;
    const short* wph  = wp + 40960;
    const short* wpo  = wp + 40960 + 3*65536;

    float4v acc[4][4];
    short8 bcur[4], bnxt[4];
    // ---- layer 0 (K=160, 5 kt) ----
    #pragma unroll
    for (int mt = 0; mt < 4; ++mt)
        #pragma unroll
        for (int nt = 0; nt < 4; ++nt) acc[mt][nt] = (float4v){0.f,0.f,0.f,0.f};
    {
        const short* bp = wp + ((size_t)ntb*64 + l)*8;
        #pragma unroll
        for (int nt = 0; nt < 4; ++nt) bcur[nt] = *(const short8*)(bp + (size_t)nt*512);
    }
    for (int kt = 0; kt < 5; ++kt) {
        if (kt < 4) {
            const short* bp = wp + ((size_t)((kt+1)*16 + ntb)*64 + l)*8;
            #pragma unroll
            for (int nt = 0; nt < 4; ++nt) bnxt[nt] = *(const short8*)(bp + (size_t)nt*512);
        }
        #pragma unroll
        for (int mt = 0; mt < 4; ++mt) {
            short8 a = *(const short8*)&act_s[(mt*16 + m_l)*264 + kt*32 + q*8];
            #pragma unroll
            for (int nt = 0; nt < 4; ++nt)
                acc[mt][nt] = __builtin_amdgcn_mfma_f32_16x16x32_bf16(a, bcur[nt], acc[mt][nt], 0, 0, 0);
        }
        if (kt < 4) {
            #pragma unroll
            for (int nt = 0; nt < 4; ++nt) bcur[nt] = bnxt[nt];
        }
    }
    __syncthreads();
    #pragma unroll
    for (int nt = 0; nt < 4; ++nt) {
        int n = (ntb + nt)*16 + m_l;
        float bias = b_in[n];
        #pragma unroll
        for (int mt = 0; mt < 4; ++mt)
            #pragma unroll
            for (int r = 0; r < 4; ++r) {
                float vv = fmaxf(acc[mt][nt][r] + bias, 0.f);
                act_s[(mt*16 + q*4 + r)*264 + n] = f2bs(vv);
            }
    }
    __syncthreads();
    // ---- hidden layers (K=256, 8 kt) ----
    for (int L = 0; L < 3; ++L) {
        #pragma unroll
        for (int mt = 0; mt < 4; ++mt)
            #pragma unroll
            for (int nt = 0; nt < 4; ++nt) acc[mt][nt] = (float4v){0.f,0.f,0.f,0.f};
        const short* wl = wph + (size_t)L * 65536;
        {
            const short* bp = wl + ((size_t)ntb*64 + l)*8;
            #pragma unroll
            for (int nt = 0; nt < 4; ++nt) bcur[nt] = *(const short8*)(bp + (size_t)nt*512);
        }
        for (int kt = 0; kt < 8; ++kt) {
            if (kt < 7) {
                const short* bp = wl + ((size_t)((kt+1)*16 + ntb)*64 + l)*8;
                #pragma unroll
                for (int nt = 0; nt < 4; ++nt) bnxt[nt] = *(const short8*)(bp + (size_t)nt*512);
            }
            #pragma unroll
            for (int mt = 0; mt < 4; ++mt) {
                short8 a = *(const short8*)&act_s[(mt*16 + m_l)*264 + kt*32 + q*8];
                #pragma unroll
                for (int nt = 0; nt < 4; ++nt)
                    acc[mt][nt] = __builtin_amdgcn_mfma_f32_16x16x32_bf16(a, bcur[nt], acc[mt][nt], 0, 0, 0);
            }
            if (kt < 7) {
                #pragma unroll
                for (int nt = 0; nt < 4; ++nt) bcur[nt] = bnxt[nt];
            }
        }
        __syncthreads();
        #pragma unroll
        for (int nt = 0; nt < 4; ++nt) {
            int n = (ntb + nt)*16 + m_l;
            float bias = b_h[L*256 + n];
            #pragma unroll
            for (int mt = 0; mt < 4; ++mt)
                #pragma unroll
                for (int r = 0; r < 4; ++r) {
                    float vv = fmaxf(acc[mt][nt][r] + bias, 0.f);
                    act_s[(mt*16 + q*4 + r)*264 + n] = f2bs(vv);
                }
        }
        __syncthreads();
    }
    // ---- output layer (N=16): wave 0 only ----
    if (w == 0) {
        float4v o[4];
        #pragma unroll
        for (int mt = 0; mt < 4; ++mt) o[mt] = (float4v){0.f,0.f,0.f,0.f};
        for (int kt = 0; kt < 8; ++kt) {
            short8 bf = *(const short8*)(wpo + ((size_t)kt*64 + l)*8);
            #pragma unroll
            for (int mt = 0; mt < 4; ++mt) {
                short8 a = *(const short8*)&act_s[(mt*16 + m_l)*264 + kt*32 + q*8];
                o[mt] = __builtin_amdgcn_mfma_f32_16x16x32_bf16(a, bf, o[mt], 0, 0, 0);
            }
        }
        float bias = b_out[m_l];
        #pragma unroll
        for (int mt = 0; mt < 4; ++mt) {
            #pragma unroll
            for (int r = 0; r < 4; ++r) {
                long P = P0 + mt*16 + q*4 + r;
                int bb = (int)(P >> 16), pim = (int)(P & 65535);
                int s0 = pim >> 8, s1 = pim & 255;
                float w0 = (s0 == 255 || s1 == 255) ? 0.25f : 1.0f;
                fo[(((long)(bb*16 + m_l)) << 16) + pim] = w0 * (o[mt][r] + bias);
            }
        }
    }
}

// ---------------- LIIF MLP edge corners via MFMA (48 blocks) ---------------------
__global__ __launch_bounds__(256) void mlp_edge_mfma_k(const short* __restrict__ feat,
        const short* __restrict__ wp,
        const float* __restrict__ b_in, const float* __restrict__ b_h,
        const float* __restrict__ b_out,
        float* __restrict__ fo){
    extern __shared__ short act_s[];
    int tid = threadIdx.x, bx = blockIdx.x;
    int E0 = bx * 128;
    for (int idx = tid; idx < 128*160; idx += 256) {
        int pp = idx / 160, j = idx - pp*160;
        int e = E0 + pp; if (e >= 6132) e = 0;
        int bb = e / 1533; int rem = e - bb*1533;
        int cn = rem / 511; int eidx = rem - cn*511;
        int s0 = (eidx < 256) ? 255 : eidx - 256;
        int s1 = (eidx < 256) ? eidx : 255;
        int vx = (cn == 0) ? -1 : 1;
        int vy = (cn == 1) ? -1 : 1;
        int i0 = (vx > 0) ? min(s0+1, 255) : s0;
        int i1 = (vy > 0) ? min(s1+1, 255) : s1;
        short v = 0;
        if (j < 144) {
            int iy = j/48, ix = (j>>4)%3, c2 = j&15;
            int yy = i0 + iy - 1, xx = i1 + ix - 1;
            if (yy >= 0 && yy < 256 && xx >= 0 && xx < 256)
                v = feat[((((long)bb << 16) + (yy<<8) + xx) << 4) + c2];
        } else if (j == 144) v = f2bs(2.f*(float)(s0 - i0));
        else if (j == 145) v = f2bs(2.f*(float)(s1 - i1));
        else if (j >= 146) v = 0x4000;
        act_s[pp*264 + j] = v;
    }
    __syncthreads();

    int l = tid & 63, w = tid >> 6;
    int m_l = l & 15, q = l >> 4;
    int row0 = w * 32;
    const short* wph  = wp + 40960;
    const short* wpo  = wp + 40960 + 3*65536;

    float4v acc[2][16];
    #pragma unroll
    for (int mt = 0; mt < 2; ++mt)
        #pragma unroll
        for (int nt = 0; nt < 16; ++nt) acc[mt][nt] = (float4v){0.f,0.f,0.f,0.f};
    for (int kt = 0; kt < 5; ++kt) {
        short8 a0 = *(const short8*)&act_s[(row0 + m_l)*264 + kt*32 + q*8];
        short8 a1 = *(const short8*)&act_s[(row0 + 16 + m_l)*264 + kt*32 + q*8];
        const short* bp = wp + ((size_t)(kt*16)*64 + l)*8;
        #pragma unroll
        for (int nt = 0; nt < 16; ++nt) {
            short8 bf = *(const short8*)(bp + (size_t)nt*64*8);
            acc[0][nt] = __builtin_amdgcn_mfma_f32_16x16x32_bf16(a0, bf, acc[0][nt], 0, 0, 0);
            acc[1][nt] = __builtin_amdgcn_mfma_f32_16x16x32_bf16(a1, bf, acc[1][nt], 0, 0, 0);
        }
    }
    #pragma unroll
    for (int nt = 0; nt < 16; ++nt) {
        float bias = b_in[nt*16 + m_l];
        #pragma unroll
        for (int mt = 0; mt < 2; ++mt)
            #pragma unroll
            for (int r = 0; r < 4; ++r) {
                float vv = fmaxf(acc[mt][nt][r] + bias, 0.f);
                act_s[(row0 + mt*16 + q*4 + r)*264 + nt*16 + m_l] = f2bs(vv);
            }
    }
    for (int L = 0; L < 3; ++L) {
        #pragma unroll
        for (int mt = 0; mt < 2; ++mt)
            #pragma unroll
            for (int nt = 0; nt < 16; ++nt) acc[mt][nt] = (float4v){0.f,0.f,0.f,0.f};
        const short* wl = wph + (size_t)L * 65536;
        for (int kt = 0; kt < 8; ++kt) {
            short8 a0 = *(const short8*)&act_s[(row0 + m_l)*264 + kt*32 + q*8];
            short8 a1 = *(const short8*)&act_s[(row0 + 16 + m_l)*264 + kt*32 + q*8];
            const short* bp = wl + ((size_t)(kt*16)*64 + l)*8;
            #pragma unroll
            for (int nt = 0; nt < 16; ++nt) {
                short8 bf = *(const short8*)(bp + (size_t)nt*64*8);
                acc[0][nt] = __builtin_amdgcn_mfma_f32_16x16x32_bf16(a0, bf, acc[0][nt], 0, 0, 0);
                acc[1][nt] = __builtin_amdgcn_mfma_f32_16x16x32_bf16(a1, bf, acc[1][nt], 0, 0, 0);
            }
        }
        #pragma unroll
        for (int nt = 0; nt < 16; ++nt) {
            float bias = b_h[L*256 + nt*16 + m_l];
            #pragma unroll
            for (int mt = 0; mt < 2; ++mt)
                #pragma unroll
                for (int r = 0; r < 4; ++r) {
                    float vv = fmaxf(acc[mt][nt][r] + bias, 0.f);
                    act_s[(row0 + mt*16 + q*4 + r)*264 + nt*16 + m_l] = f2bs(vv);
                }
        }
    }
    float4v o0 = (float4v){0.f,0.f,0.f,0.f}, o1 = (float4v){0.f,0.f,0.f,0.f};
    for (int kt = 0; kt < 8; ++kt) {
        short8 a0 = *(const short8*)&act_s[(row0 + m_l)*264 + kt*32 + q*8];
        short8 a1 = *(const short8*)&act_s[(row0 + 16 + m_l)*264 + kt*32 + q*8];
        short8 bf = *(const short8*)(wpo + ((size_t)kt*64 + l)*8);
        o0 = __builtin_amdgcn_mfma_f32_16x16x32_bf16(a0, bf, o0, 0, 0, 0);
        o1 = __builtin_amdgcn_mfma_f32_16x16x32_bf16(a1, bf, o1, 0, 0, 0);
    }
    float bias = b_out[m_l];
    #pragma unroll
    for (int mt = 0; mt < 2; ++mt) {
        float4v* op = mt ? &o1 : &o0;
        #pragma unroll
        for (int r = 0; r < 4; ++r) {
            int e = E0 + row0 + mt*16 + q*4 + r;
            float scale = (e < 6132) ? 0.25f : 0.f;
            if (e >= 6132) e = 0;
            int bb = e / 1533; int rem = e - bb*1533;
            int cn = rem / 511; int eidx = rem - cn*511;
            int s0 = (eidx < 256) ? 255 : eidx - 256;
            int s1 = (eidx < 256) ? eidx : 255;
            atomicAdd(&fo[(((long)(bb*16 + m_l)) << 16) + (s0<<8) + s1],
                      scale * ((*op)[r] + bias));
        }
    }
}

// ---------------- final conv (16->4) + lrms_up -----------------------------------
__global__ __launch_bounds__(256) void final_k(const float* __restrict__ fo, const float* __restrict__ w,
                                               const float* __restrict__ lrms_up, float* __restrict__ out){
    int tid = threadIdx.x, bx = blockIdx.x;
    int y = bx & 255, oc = (bx >> 8) & 3, b = bx >> 10;
    int x = tid;
    const float* wg = w + (size_t)oc * 144;
    float acc = 0.f;
    for (int ic = 0; ic < 16; ++ic) {
        const float* base = fo + (((size_t)(b*16 + ic)) << 16);
        #pragma unroll
        for (int ky = 0; ky < 3; ++ky) {
            int yy = y + ky - 1; if (yy < 0 || yy > 255) continue;
            const float* rowp = base + (yy<<8);
            float v0 = (x > 0)   ? rowp[x-1] : 0.f;
            float v1 = rowp[x];
            float v2 = (x < 255) ? rowp[x+1] : 0.f;
            const float* wr = wg + ic*9 + ky*3;
            acc = fmaf(wr[0], v0, fmaf(wr[1], v1, fmaf(wr[2], v2, acc)));
        }
    }
    size_t oidx = (((size_t)(b*4 + oc)) << 16) + (y<<8) + x;
    out[oidx] = acc + lrms_up[oidx];
}

// ================================================================================
extern "C" void kernel_launch(void* const* d_in, const int* in_sizes, int n_in,
                              void* d_out, int out_size, void* d_ws, size_t ws_size,
                              hipStream_t stream) {
    const float* lrms     = (const float*)d_in[0];
    const float* pan      = (const float*)d_in[1];
    const float* w_convps = (const float*)d_in[2];
    const float* hor_w1   = (const float*)d_in[3];
    const float* hor_w2   = (const float*)d_in[4];
    const float* ffc_l2l  = (const float*)d_in[5];
    const float* ffc_l2g  = (const float*)d_in[6];
    const float* ffc_g2l  = (const float*)d_in[7];
    const float* ffc_spec = (const float*)d_in[8];
    const float* ref_in   = (const float*)d_in[9];
    const float* ref_b1   = (const float*)d_in[10];
    const float* ref_b2   = (const float*)d_in[11];
    const float* ref_ca1  = (const float*)d_in[12];
    const float* ref_ca2  = (const float*)d_in[13];
    const float* ref_out  = (const float*)d_in[14];
    const float* w_fuse   = (const float*)d_in[15];
    const float* w_liif   = (const float*)d_in[16];
    const float* w_hp     = (const float*)d_in[17];
    const float* mw_in    = (const float*)d_in[18];
    const float* mb_in    = (const float*)d_in[19];
    const float* mw_h     = (const float*)d_in[20];
    const float* mb_h     = (const float*)d_in[21];
    const float* mw_out   = (const float*)d_in[22];
    const float* mb_out   = (const float*)d_in[23];
    float* out = (float*)d_out;

    const size_t PLANE = 65536;
    char* base = (char*)d_ws;
    size_t off = 0;
    auto alloc = [&](size_t bytes){ void* p = base + off; off += (bytes + 255) & ~(size_t)255; return p; };
    float* lrms_up  = (float*)alloc(16*PLANE*4);
    bf16*  feat2    = (bf16*) alloc(24*PLANE*2);
    bf16*  bA       = (bf16*) alloc(192*PLANE*2);
    bf16*  bB       = (bf16*) alloc(192*PLANE*2);
    bf16*  bC       = (bf16*) alloc(192*PLANE*2);
    bf16*  bF       = (bf16*) alloc(192*PLANE*2);
    bf16*  fusedCat = (bf16*) alloc(192*PLANE*2);
    bf16*  feat_all = (bf16*) alloc(64*PLANE*2);
    float* fo       = (float*)alloc(64*PLANE*4);
    const size_t FFTB = (size_t)3*4*8*256*129;
    bf16* re0 = (bf16*)alloc(FFTB*2); bf16* im0 = (bf16*)alloc(FFTB*2);
    bf16* re1 = (bf16*)alloc(FFTB*2); bf16* im1 = (bf16*)alloc(FFTB*2);
    short* wpack = (short*)alloc(241664*2);
    short* wconv = (short*)alloc(45*2560*2);
    float* means3 = (float*)alloc(3*192*4);
    if (off > ws_size) return;

    hipMemsetAsync(means3, 0, 3*192*4, stream);
    init_k<<<dim3(4096 + 1395), dim3(256), 0, stream>>>(lrms, w_convps, lrms_up,
        mw_in, mw_h, mw_out, hor_w2, ref_in, ref_b1, ref_b2, ref_out,
        ffc_l2l, ffc_l2g, ffc_g2l, wpack, wconv);

    GK3 g3;
    {
        const int kss[3] = {5, 27, 41};
        const double sgs[3] = {1.5, 2.0, 2.8};
        for (int br = 0; br < 3; ++br) {
            g3.ks[br] = kss[br];
            double tmp[41]; double s = 0.0; double c = (kss[br]-1)/2.0;
            for (int i = 0; i < kss[br]; ++i) { double d = i - c; tmp[i] = exp(-(d*d)/(2.0*sgs[br]*sgs[br])); s += tmp[i]; }
            for (int i = 0; i < 41; ++i) g3.k[br][i] = (i < kss[br]) ? (float)(tmp[i]/s) : 0.f;
        }
    }
    gauss_hp_k<<<dim3(6144), dim3(256), 0, stream>>>(pan, lrms_up, feat2, g3);

    // hornet
    convA_k<<<dim3(3072), dim3(256), 0, stream>>>(feat2, 2, 2, hor_w1, 720, 45, bA, ACT_GELU);
    convM_k<<<dim3(768), dim3(256), 0, stream>>>(bA, wconv + 0*3*2560, bB, ACT_NONE, nullptr);

    for (int step = 0; step < 3; ++step) {
        bf16* Xin = (step == 0) ? bB : bA;
        bf16* Yb  = (step == 0) ? bA : bB;
        bf16* Db  = (step == 0) ? bB : bA;
        convM_k<<<dim3(768), dim3(256), 0, stream>>>(Xin, wconv + (1+step)*3*2560, Yb, ACT_NONE, nullptr);
        convM_k<<<dim3(768), dim3(256), 0, stream>>>(Yb,  wconv + (4+step)*3*2560, bC, ACT_RELU, nullptr);
        convM_k<<<dim3(768), dim3(256), 0, stream>>>(bC,  wconv + (7+step)*3*2560, Db, ACT_NONE, means3 + step*192);
        convOutM_k<<<dim3(768), dim3(256), 0, stream>>>(Yb, Db, means3 + step*192, ref_ca1, ref_ca2,
                                                        wconv + (12+step)*3*2560, w_fuse, step, bF, fusedCat);
        if (step < 2) {
            convM_k<<<dim3(768), dim3(256), 0, stream>>>(bF, wconv + (10+step)*3*2560, bA, ACT_NONE, nullptr);
            rfft_wT_k<<<dim3(1536), dim3(256), 32768, stream>>>(bF, re0, im0);
            fftspec_hT_k<<<dim3(1548), dim3(256), 0, stream>>>(re0, im0, ffc_spec, step, re1, im1);
            irfft_wT_k<<<dim3(1536), dim3(256), 32768, stream>>>(re1, im1, bA);
        }
    }

    fuse1x1_k<<<dim3(1024), dim3(256), 0, stream>>>(fusedCat, w_liif, feat_all);
    mlp_mfma_k<<<dim3(4096), dim3(256), 64*264*2, stream>>>((const short*)feat_all, wpack, mb_in, mb_h, mb_out, fo);
    mlp_edge_mfma_k<<<dim3(48), dim3(256), 128*264*2, stream>>>((const short*)feat_all, wpack, mb_in, mb_h, mb_out, fo);
    final_k<<<dim3(4096), dim3(256), 0, stream>>>(fo, w_hp, lrms_up, out);
}

// Round 12
// 1181.944 us; speedup vs baseline: 1.0070x; 1.0070x over previous
//
#include <hip/hip_runtime.h>
#include <hip/hip_bf16.h>
#include <math.h>

typedef __hip_bfloat16 bf16;
typedef __attribute__((ext_vector_type(8))) short short8;
typedef __attribute__((ext_vector_type(4))) short short4v;
typedef __attribute__((ext_vector_type(4))) float float4v;

#define ACT_NONE 0
#define ACT_RELU 1
#define ACT_GELU 2

__device__ __forceinline__ float b2f(bf16 v){ return __bfloat162float(v); }
__device__ __forceinline__ bf16  f2b(float f){ return __float2bfloat16(f); }
__device__ __forceinline__ short f2bs(float f){ bf16 h = __float2bfloat16(f); return *reinterpret_cast<short*>(&h); }
__device__ __forceinline__ float bs2f(short s){ return __uint_as_float(((unsigned)(unsigned short)s) << 16); }
__device__ __forceinline__ void rotc(float& tr, float& ti, float cr, float ci){
    float t = tr*cr - ti*ci; ti = tr*ci + ti*cr; tr = t;
}

struct GK3 { float k[3][41]; int ks[3]; };

// ---------------- merged init: conv_ps (bx<4096) + weight packing ----------------
__global__ __launch_bounds__(256) void init_k(const float* __restrict__ lrms,
        const float* __restrict__ wps, float* __restrict__ up,
        const float* __restrict__ mw_in, const float* __restrict__ mw_h,
        const float* __restrict__ mw_out, const float* __restrict__ hor_w2,
        const float* __restrict__ ref_in, const float* __restrict__ ref_b1,
        const float* __restrict__ ref_b2, const float* __restrict__ ref_out,
        const float* __restrict__ l2l, const float* __restrict__ l2g,
        const float* __restrict__ g2l,
        short* __restrict__ wp, short* __restrict__ wc){
    int tid = threadIdx.x, bx = blockIdx.x;
    if (bx < 4096) {
        int y = bx & 255, c = (bx >> 8) & 3, b = bx >> 10;
        int x = tid;
        int h = y >> 2, r1 = y & 3, ww = x >> 2, r2 = x & 3;
        int oc = c*16 + r1*4 + r2;
        float acc = 0.f;
        for (int ic = 0; ic < 4; ++ic) {
            const float* base = lrms + ((b*4 + ic) << 12);
            const float* wb = wps + (oc*4 + ic)*9;
            #pragma unroll
            for (int ky = 0; ky < 3; ++ky) {
                int hh = h + ky - 1; if (hh < 0 || hh > 63) continue;
                #pragma unroll
                for (int kx = 0; kx < 3; ++kx) {
                    int cc = ww + kx - 1; if (cc < 0 || cc > 63) continue;
                    acc += base[(hh<<6) + cc] * wb[ky*3 + kx];
                }
            }
        }
        up[(((size_t)(b*4 + c)) << 16) + (y<<8) + x] = acc;
        return;
    }
    int idx = (bx - 4096)*256 + tid;
    const int S0 = 40960, SH = 65536;
    const int TOTM = S0 + 3*SH + 4096;
    const int TOTC = 45*2560;
    if (idx < TOTM) {
        float val;
        if (idx < S0) {
            int j = idx & 7, l = (idx>>3) & 63, nt = (idx>>9) & 15, kt = idx >> 13;
            int k = kt*32 + (l>>4)*8 + j;
            int n = nt*16 + (l&15);
            val = (k < 148) ? mw_in[k*256 + n] : 0.f;
        } else if (idx < S0 + 3*SH) {
            int i2 = idx - S0;
            int L = i2 >> 16, r = i2 & 65535;
            int j = r & 7, l = (r>>3) & 63, nt = (r>>9) & 15, kt = r >> 13;
            int k = kt*32 + (l>>4)*8 + j;
            int n = nt*16 + (l&15);
            val = mw_h[L*65536 + k*256 + n];
        } else {
            int i3 = idx - S0 - 3*SH;
            int j = i3 & 7, l = (i3>>3) & 63, kt = i3 >> 9;
            int k = kt*32 + (l>>4)*8 + j;
            int oc = l & 15;
            val = mw_out[k*16 + oc];
        }
        wp[idx] = f2bs(val);
        return;
    }
    int idx2 = idx - TOTM;
    if (idx2 >= TOTC) return;
    int set = idx2 / 2560, r = idx2 % 2560;
    int j = r & 7, l = (r>>3) & 63, kt = r >> 9;
    int k = kt*32 + ((l>>4)&3)*8 + j;
    int n = l & 15;
    int g = set / 3, br = set % 3;
    float v = 0.f;
    if (k < 144) {
        int tap = k >> 4, ic = k & 15;
        if (g == 10 || g == 11) {
            int wi = 2*br + (g-10);
            if (n < 8) v = (ic < 8) ? l2g[((wi*8 + n)*8 + ic)*9 + tap] : 0.f;
            else {
                int o = n - 8;
                v = (ic < 8) ? l2l[((wi*8 + o)*8 + ic)*9 + tap]
                             : g2l[((wi*8 + o)*8 + (ic-8))*9 + tap];
            }
        } else {
            int widx = (n*16 + ic)*9 + tap;
            const float* src;
            if (g == 0)       src = hor_w2 + br*2304;
            else if (g <= 3)  src = ref_in + (3*br + (g-1))*2304;
            else if (g <= 6)  src = ref_b1 + (3*br + (g-4))*2304;
            else if (g <= 9)  src = ref_b2 + (3*br + (g-7))*2304;
            else              src = ref_out + (3*br + (g-12))*2304;
            v = src[widx];
        }
    }
    wc[idx2] = f2bs(v);
}

// ---------------- fused gaussian highpass -------------------------------------
__global__ __launch_bounds__(256) void gauss_hp_k(const float* __restrict__ pan,
                                                  const float* __restrict__ lrms_up,
                                                  bf16* __restrict__ feat2, GK3 g){
    int tid = threadIdx.x, bx = blockIdx.x;
    int y = bx & 255, b = (bx >> 8) & 3, src = (bx >> 10) & 1, br = bx >> 11;
    int ks = g.ks[br], p = ks >> 1;
    const float* gk = g.k[br];
    const float* s = src ? (lrms_up + (size_t)b*4*65536) : (pan + (size_t)b*65536);
    __shared__ float vext[296];
    for (int i = tid; i < 296; i += 256) {
        int xe = i - 20; int xr = xe < 0 ? -xe : (xe > 255 ? 510 - xe : xe);
        float acc = 0.f;
        for (int t = 0; t < ks; ++t) {
            int yy = y - p + t; yy = yy < 0 ? -yy : (yy > 255 ? 510 - yy : yy);
            acc += gk[t] * s[(yy<<8) + xr];
        }
        vext[i] = acc;
    }
    __syncthreads();
    int x = tid;
    float acc = 0.f;
    for (int t = 0; t < ks; ++t) acc += gk[t] * vext[x - p + t + 20];
    float o = s[(y<<8) + x];
    feat2[(((size_t)((br*4 + b)*2 + src)) << 16) + (y<<8) + x] = f2b(o - acc);
}

// ---------------- scalar 3x3 conv (hornet conv1, Cin=2) -------------------------
__global__ __launch_bounds__(256) void convA_k(const bf16* __restrict__ in, int inCper, int Cin,
                                               const float* __restrict__ wbase, int wbrstride, int wocstride,
                                               bf16* __restrict__ out, int act){
    int tid = threadIdx.x, bx = blockIdx.x;
    int y = bx & 255, b = (bx >> 8) & 3, br = bx >> 10;
    const float* w = wbase + (size_t)br * wbrstride;
    int x = tid;
    float acc[16];
    #pragma unroll
    for (int oc = 0; oc < 16; ++oc) acc[oc] = 0.f;
    for (int ic = 0; ic < Cin; ++ic) {
        const bf16* base = in + ((size_t)((br*4 + b)*inCper + ic) << 16);
        const float* wic = w + ic*9;
        #pragma unroll
        for (int ky = 0; ky < 3; ++ky) {
            int yy = y + ky - 1; if (yy < 0 || yy > 255) continue;
            const bf16* rowp = base + (yy<<8);
            float v0 = (x > 0)   ? b2f(rowp[x-1]) : 0.f;
            float v1 = b2f(rowp[x]);
            float v2 = (x < 255) ? b2f(rowp[x+1]) : 0.f;
            const float* wr = wic + ky*3;
            #pragma unroll
            for (int oc = 0; oc < 16; ++oc) {
                const float* wo = wr + oc*wocstride;
                acc[oc] = fmaf(wo[0], v0, fmaf(wo[1], v1, fmaf(wo[2], v2, acc[oc])));
            }
        }
    }
    #pragma unroll
    for (int oc = 0; oc < 16; ++oc) {
        float a = acc[oc];
        if (act == ACT_RELU) a = fmaxf(a, 0.f);
        else if (act == ACT_GELU) {
            float u = 0.7978845608028654f * (a + 0.044715f*a*a*a);
            a = 0.5f * a * (1.f + tanhf(u));
        }
        out[((size_t)((br*4 + b)*16 + oc) << 16) + (y<<8) + x] = f2b(a);
    }
}

// ---------------- MFMA 3x3 conv, 4 output rows per block ------------------------
// pad region k>=144 has zero-packed weights; tap clamped to 8 keeps LDS reads in-bounds.
__global__ __launch_bounds__(256) void convM_k(const bf16* __restrict__ in,
        const short* __restrict__ wgroup,
        bf16* __restrict__ out, int act, float* __restrict__ means){
    __shared__ short sIn[6*258*20];
    __shared__ float sm[4][16];
    int tid = threadIdx.x, bx = blockIdx.x;
    int y0 = (bx & 63) << 2, b = (bx >> 6) & 3, br = bx >> 8;
    size_t pbase = (size_t)((br*4 + b)*16) << 16;
    if (tid < 192) {
        int r = tid >> 5, side = (tid >> 4) & 1, ic = tid & 15;
        sIn[(r*258 + (side ? 257 : 0))*20 + ic] = 0;
    }
    {
        int g = tid >> 5, tl = tid & 31, x0 = tl << 3, ic0 = g*2;
        for (int r = 0; r < 6; ++r) {
            int yy = y0 - 1 + r;
            short8 lo = {0,0,0,0,0,0,0,0}, hi = {0,0,0,0,0,0,0,0};
            if (yy >= 0 && yy <= 255) {
                lo = *(const short8*)&in[pbase + ((size_t)ic0<<16) + (yy<<8) + x0];
                hi = *(const short8*)&in[pbase + ((size_t)(ic0+1)<<16) + (yy<<8) + x0];
            }
            #pragma unroll
            for (int t = 0; t < 8; ++t) {
                int v = (int)(unsigned short)lo[t] | ((int)(unsigned short)hi[t] << 16);
                *(int*)&sIn[(r*258 + x0 + t + 1)*20 + ic0] = v;
            }
        }
    }
    __syncthreads();
    int l = tid & 63, w = tid >> 6, m_l = l & 15, q = l >> 4;
    const short* wp = wgroup + br*2560;
    short8 bfr[5];
    #pragma unroll
    for (int kt = 0; kt < 5; ++kt)
        bfr[kt] = *(const short8*)(wp + (kt*64 + l)*8);
    float4v acc[16];
    #pragma unroll
    for (int j = 0; j < 16; ++j) acc[j] = (float4v){0.f,0.f,0.f,0.f};
    #pragma unroll
    for (int kt = 0; kt < 5; ++kt) {
        int k0 = kt*32 + q*8;
        int tap = k0 >> 4; if (tap > 8) tap = 8;   // k>=144: weights are zero; stay in-bounds
        int icb = k0 & 15;
        int ky = tap/3, kx = tap - ky*3;
        int rbase = (w + ky)*258 + kx;
        #pragma unroll
        for (int j = 0; j < 16; ++j) {
            int x = j*16 + m_l;
            const short* ap = &sIn[(rbase + x)*20 + icb];
            short4v alo = *(const short4v*)ap;
            short4v ahi = *(const short4v*)(ap + 4);
            short8 a = __builtin_shufflevector(alo, ahi, 0,1,2,3,4,5,6,7);
            acc[j] = __builtin_amdgcn_mfma_f32_16x16x32_bf16(a, bfr[kt], acc[j], 0, 0, 0);
        }
    }
    if (means) {
        float s = 0.f;
        #pragma unroll
        for (int j = 0; j < 16; ++j)
            #pragma unroll
            for (int r = 0; r < 4; ++r) s += acc[j][r];
        s += __shfl_xor(s, 16, 64);
        s += __shfl_xor(s, 32, 64);
        if (l < 16) sm[w][l] = s;
        __syncthreads();
        if (tid < 16) atomicAdd(&means[br*64 + b*16 + tid],
                                sm[0][tid] + sm[1][tid] + sm[2][tid] + sm[3][tid]);
    }
    int yrow = y0 + w;
    #pragma unroll
    for (int j = 0; j < 16; ++j) {
        short4v pk;
        #pragma unroll
        for (int r = 0; r < 4; ++r) {
            float a = acc[j][r];
            if (act == ACT_RELU) a = fmaxf(a, 0.f);
            else if (act == ACT_GELU) {
                float u = 0.7978845608028654f * (a + 0.044715f*a*a*a);
                a = 0.5f * a * (1.f + tanhf(u));
            }
            pk[r] = f2bs(a);
        }
        *(short4v*)&out[pbase + ((size_t)m_l << 16) + (yrow<<8) + j*16 + q*4] = pk;
    }
}

// ---------------- MFMA refine-out conv: ca computed inline, + fuse 1x1 ----------
__global__ __launch_bounds__(256) void convOutM_k(const bf16* __restrict__ Y, const bf16* __restrict__ BDY,
        const float* __restrict__ means, const float* __restrict__ ca1, const float* __restrict__ ca2,
        const short* __restrict__ wgroup,
        const float* __restrict__ wfuse, int step,
        bf16* __restrict__ F, bf16* __restrict__ fusedCat){
    __shared__ short sIn[6*258*20];
    __shared__ float sCav[16];
    int tid = threadIdx.x, bx = blockIdx.x;
    int y0 = (bx & 63) << 2, b = (bx >> 6) & 3, br = bx >> 8;
    size_t pbase = (size_t)((br*4 + b)*16) << 16;
    if (tid < 192) {
        int r = tid >> 5, side = (tid >> 4) & 1, ic = tid & 15;
        sIn[(r*258 + (side ? 257 : 0))*20 + ic] = 0;
    }
    if (tid < 16) {
        int ri = 3*br + step;
        const float* w1 = ca1 + ri*64; const float* w2 = ca2 + ri*64;
        float hid[4];
        #pragma unroll
        for (int c2 = 0; c2 < 4; ++c2) {
            float a = 0.f;
            for (int c = 0; c < 16; ++c) a += w1[c2*16 + c] * (means[br*64 + b*16 + c] * (1.f/65536.f));
            hid[c2] = fmaxf(a, 0.f);
        }
        float v = 0.f;
        #pragma unroll
        for (int c2 = 0; c2 < 4; ++c2) v += w2[tid*4 + c2] * hid[c2];
        sCav[tid] = 1.f / (1.f + expf(-v));
    }
    __syncthreads();
    {
        int g = tid >> 5, tl = tid & 31, x0 = tl << 3, ic0 = g*2;
        float c0 = sCav[ic0];
        float c1 = sCav[ic0 + 1];
        for (int r = 0; r < 6; ++r) {
            int yy = y0 - 1 + r;
            short8 ylo = {0,0,0,0,0,0,0,0}, yhi = ylo, dlo = ylo, dhi = ylo;
            if (yy >= 0 && yy <= 255) {
                size_t o0 = pbase + ((size_t)ic0<<16) + (yy<<8) + x0;
                size_t o1 = pbase + ((size_t)(ic0+1)<<16) + (yy<<8) + x0;
                ylo = *(const short8*)&Y[o0];   yhi = *(const short8*)&Y[o1];
                dlo = *(const short8*)&BDY[o0]; dhi = *(const short8*)&BDY[o1];
            }
            #pragma unroll
            for (int t = 0; t < 8; ++t) {
                short s0 = f2bs(fmaf(bs2f(dlo[t]), c0, bs2f(ylo[t])));
                short s1 = f2bs(fmaf(bs2f(dhi[t]), c1, bs2f(yhi[t])));
                int v = (int)(unsigned short)s0 | ((int)(unsigned short)s1 << 16);
                *(int*)&sIn[(r*258 + x0 + t + 1)*20 + ic0] = v;
            }
        }
    }
    __syncthreads();
    int l = tid & 63, w = tid >> 6, m_l = l & 15, q = l >> 4;
    const short* wp = wgroup + br*2560;
    short8 bfr[5];
    #pragma unroll
    for (int kt = 0; kt < 5; ++kt)
        bfr[kt] = *(const short8*)(wp + (kt*64 + l)*8);
    float4v acc[16];
    #pragma unroll
    for (int j = 0; j < 16; ++j) acc[j] = (float4v){0.f,0.f,0.f,0.f};
    #pragma unroll
    for (int kt = 0; kt < 5; ++kt) {
        int k0 = kt*32 + q*8;
        int tap = k0 >> 4; if (tap > 8) tap = 8;
        int icb = k0 & 15;
        int ky = tap/3, kx = tap - ky*3;
        int rbase = (w + ky)*258 + kx;
        #pragma unroll
        for (int j = 0; j < 16; ++j) {
            int x = j*16 + m_l;
            const short* ap = &sIn[(rbase + x)*20 + icb];
            short4v alo = *(const short4v*)ap;
            short4v ahi = *(const short4v*)(ap + 4);
            short8 a = __builtin_shufflevector(alo, ahi, 0,1,2,3,4,5,6,7);
            acc[j] = __builtin_amdgcn_mfma_f32_16x16x32_bf16(a, bfr[kt], acc[j], 0, 0, 0);
        }
    }
    int yrow = y0 + w;
    #pragma unroll
    for (int j = 0; j < 16; ++j) {
        short4v pk;
        #pragma unroll
        for (int r = 0; r < 4; ++r) pk[r] = f2bs(acc[j][r]);
        *(short4v*)&F[pbase + ((size_t)m_l << 16) + (yrow<<8) + j*16 + q*4] = pk;
    }
    __syncthreads();            // everyone done reading sIn; reuse as sF
    short* sF = sIn + w*4096;   // per-wave 256px x 16oc
    #pragma unroll
    for (int j = 0; j < 16; ++j)
        #pragma unroll
        for (int r = 0; r < 4; ++r)
            sF[(j*16 + q*4 + r)*16 + m_l] = f2bs(acc[j][r]);
    const float* wf = wfuse + br*768 + step*16;   // wf[oc2*48 + oc]
    short8 b2;
    #pragma unroll
    for (int jj = 0; jj < 8; ++jj) {
        int k = q*8 + jj;
        b2[jj] = (k < 16) ? f2bs(wf[m_l*48 + k]) : (short)0;
    }
    #pragma unroll
    for (int mt = 0; mt < 16; ++mt) {
        short8 a2 = {0,0,0,0,0,0,0,0};
        if (q < 2) a2 = *(const short8*)&sF[(mt*16 + m_l)*16 + q*8];
        float4v d2 = (float4v){0.f,0.f,0.f,0.f};
        d2 = __builtin_amdgcn_mfma_f32_16x16x32_bf16(a2, b2, d2, 0, 0, 0);
        size_t fidx = ((size_t)(b*48 + br*16 + m_l) << 16) + (yrow<<8) + mt*16 + q*4;
        short4v pk;
        if (step == 0) {
            #pragma unroll
            for (int r = 0; r < 4; ++r) pk[r] = f2bs(d2[r]);
        } else {
            short4v old = *(const short4v*)&fusedCat[fidx];
            #pragma unroll
            for (int r = 0; r < 4; ++r) pk[r] = f2bs(bs2f(old[r]) + d2[r]);
        }
        *(short4v*)&fusedCat[fidx] = pk;
    }
}

// ---------------- radix-16 rfft, TRANSPOSED out, bf16 LDS (~25KB) ----------------
__global__ __launch_bounds__(256) void rfft_wT_k(const bf16* __restrict__ F,
                                                 bf16* __restrict__ ore, bf16* __restrict__ oim){
    __shared__ short ubuf[4386];        // rows[16][256] (4096) overlapped with Tr/Ti (2x2193)
    __shared__ short2 Acx[4096];        // stage-1 complex, bf16 pair
    short (*rows)[256] = (short(*)[256])ubuf;
    short (*Tr)[17] = (short(*)[17])ubuf;
    short (*Ti)[17] = (short(*)[17])(ubuf + 2193);
    int tid = threadIdx.x, bx = blockIdx.x;
    int t = bx & 15, c = (bx >> 4) & 7, b = (bx >> 7) & 3, br = bx >> 9;
    int y0 = t << 4;
    size_t plane = (size_t)((br*4 + b)*16 + 8 + c) << 16;
    #pragma unroll
    for (int r = 0; r < 16; ++r)
        rows[r][tid] = *(const short*)&F[plane + ((size_t)(y0 + r) << 8) + tid];
    __syncthreads();
    int n1 = tid >> 4, k1 = tid & 15;
    float a1 = -6.283185307179586f * (float)k1 / 16.f;
    float c1, s1; __sincosf(a1, &s1, &c1);
    for (int r = 0; r < 16; ++r) {
        float twr = 1.f, twi = 0.f, ar = 0.f, ai = 0.f;
        #pragma unroll
        for (int n2 = 0; n2 < 16; ++n2) {
            float xr = bs2f(rows[r][n1 + (n2<<4)]);
            ar = fmaf(xr, twr, ar); ai = fmaf(xr, twi, ai);
            rotc(twr, twi, c1, s1);
        }
        short2 pk; pk.x = f2bs(ar); pk.y = f2bs(ai);
        Acx[r*256 + tid] = pk;
    }
    __syncthreads();
    if (tid < 129) {
        int kk1 = tid & 15;
        float a2 = -6.283185307179586f * (float)tid / 256.f;
        float c2v, s2v; __sincosf(a2, &s2v, &c2v);
        for (int r = 0; r < 16; ++r) {
            float t2r = 1.f, t2i = 0.f, re = 0.f, im = 0.f;
            #pragma unroll
            for (int m = 0; m < 16; ++m) {
                short2 A = Acx[r*256 + (m<<4) + kk1];
                float Ax = bs2f(A.x), Ay = bs2f(A.y);
                re += Ax*t2r - Ay*t2i; im += Ay*t2r + Ax*t2i;
                rotc(t2r, t2i, c2v, s2v);
            }
            Tr[tid][r] = f2bs(re * 0.0625f); Ti[tid][r] = f2bs(im * 0.0625f);
        }
    }
    __syncthreads();
    size_t obase = ((size_t)(((br*4 + b)*8 + c)*129)) * 256 + y0;
    for (int idx = tid; idx < 129*16; idx += 256) {
        int k = idx >> 4, ty = idx & 15;
        *(short*)&ore[obase + (size_t)k*256 + ty] = Tr[k][ty];
        *(short*)&oim[obase + (size_t)k*256 + ty] = Ti[k][ty];
    }
}

// ---------------- FUSED fft_h fwd -> spec -> fft_h inv, barrier-batched ----------
__global__ __launch_bounds__(256) void fftspec_hT_k(const bf16* __restrict__ re0, const bf16* __restrict__ im0,
                                                    const float* __restrict__ wspec, int step,
                                                    bf16* __restrict__ re1, bf16* __restrict__ im1){
    __shared__ float2 Fc[8][256];
    __shared__ float2 Sc[8][256];
    int tid = threadIdx.x, bx = blockIdx.x;
    int k = bx % 129; int r2 = bx / 129; int b = r2 & 3, br = r2 >> 2;
    size_t cb = (size_t)((br*4 + b)*8) * 33024 + (size_t)k * 256;
    int n1 = tid >> 4, k1 = tid & 15;
    float a1 = -6.283185307179586f * (float)k1 / 16.f;
    float c1, s1; __sincosf(a1, &s1, &c1);
    float a2 = -6.283185307179586f * (float)tid / 256.f;
    float c2v, s2v; __sincosf(a2, &s2v, &c2v);
    #pragma unroll
    for (int c = 0; c < 8; ++c) {
        size_t base = cb + (size_t)c*33024 + tid;
        Fc[c][tid] = make_float2(b2f(re0[base]), b2f(im0[base]));
    }
    __syncthreads();
    for (int c = 0; c < 8; ++c) {
        float twr = 1.f, twi = 0.f, ar = 0.f, ai = 0.f;
        #pragma unroll
        for (int n2 = 0; n2 < 16; ++n2) {
            float2 x = Fc[c][n1 + (n2<<4)];
            ar += x.x*twr - x.y*twi; ai += x.y*twr + x.x*twi;
            rotc(twr, twi, c1, s1);
        }
        Sc[c][tid] = make_float2(ar, ai);
    }
    __syncthreads();
    for (int c = 0; c < 8; ++c) {
        float t2r = 1.f, t2i = 0.f, rr = 0.f, ii = 0.f;
        #pragma unroll
        for (int m = 0; m < 16; ++m) {
            float2 A = Sc[c][(m<<4) + k1];
            rr += A.x*t2r - A.y*t2i; ii += A.y*t2r + A.x*t2i;
            rotc(t2r, t2i, c2v, s2v);
        }
        Fc[c][tid] = make_float2(rr * 0.0625f, ii * 0.0625f);
    }
    __syncthreads();
    {
        const float* wl = wspec + (2*br + step)*256;
        float outv[16];
        #pragma unroll
        for (int oc = 0; oc < 16; ++oc) {
            float acc = 0.f;
            #pragma unroll
            for (int ic = 0; ic < 8; ++ic) {
                float2 gv = Fc[ic][tid];
                acc += gv.x * wl[oc*16 + ic] + gv.y * wl[oc*16 + 8 + ic];
            }
            outv[oc] = fmaxf(acc, 0.f);
        }
        __syncthreads();
        #pragma unroll
        for (int oc = 0; oc < 8; ++oc) Sc[oc][tid] = make_float2(outv[oc], outv[oc+8]);
    }
    __syncthreads();
    for (int c = 0; c < 8; ++c) {
        float twr = 1.f, twi = 0.f, ar = 0.f, ai = 0.f;
        #pragma unroll
        for (int n2 = 0; n2 < 16; ++n2) {
            float2 x = Sc[c][n1 + (n2<<4)];
            ar += x.x*twr + x.y*twi;
            ai += x.y*twr - x.x*twi;
            rotc(twr, twi, c1, s1);
        }
        Fc[c][tid] = make_float2(ar, ai);
    }
    __syncthreads();
    for (int c = 0; c < 8; ++c) {
        float t2r = 1.f, t2i = 0.f, rr = 0.f, ii = 0.f;
        #pragma unroll
        for (int m = 0; m < 16; ++m) {
            float2 A = Fc[c][(m<<4) + k1];
            rr += A.x*t2r + A.y*t2i;
            ii += A.y*t2r - A.x*t2i;
            rotc(t2r, t2i, c2v, s2v);
        }
        size_t base = cb + (size_t)c*33024 + tid;
        re1[base] = f2b(rr * 0.0625f);
        im1[base] = f2b(ii * 0.0625f);
    }
}

// ---------------- c2r irfft from [k][y], bf16 LDS (~32.5KB) ----------------------
__global__ __launch_bounds__(256) void irfft_wT_k(const bf16* __restrict__ re1, const bf16* __restrict__ im1,
                                                  bf16* __restrict__ A){
    __shared__ short2 Ecx[16][258];     // Hermitian-extended input (bf16 pair)
    __shared__ short2 Acx[4096];        // stage-1 complex (bf16 pair)
    int tid = threadIdx.x, bx = blockIdx.x;
    int t = bx & 15, c = (bx >> 4) & 7, b = (bx >> 7) & 3, br = bx >> 9;
    int y0 = t << 4;
    size_t ibase = ((size_t)(((br*4 + b)*8 + c)*129)) * 256 + y0;
    for (int idx = tid; idx < 16*256; idx += 256) {
        int i = idx >> 4, ty = idx & 15;
        int k = (i < 129) ? i : 256 - i;
        short rs = *(const short*)&re1[ibase + (size_t)k*256 + ty];
        short is = (k == 0 || k == 128) ? (short)0 : *(const short*)&im1[ibase + (size_t)k*256 + ty];
        if (i >= 129) is = (short)(is ^ (short)0x8000);
        short2 pk; pk.x = rs; pk.y = is;
        Ecx[ty][i] = pk;
    }
    __syncthreads();
    int n1 = tid >> 4, k1 = tid & 15;
    float a1 = 6.283185307179586f * (float)k1 / 16.f;
    float c1, s1; __sincosf(a1, &s1, &c1);
    for (int ty = 0; ty < 16; ++ty) {
        float twr = 1.f, twi = 0.f, ar = 0.f, ai = 0.f;
        #pragma unroll
        for (int n2 = 0; n2 < 16; ++n2) {
            short2 xs = Ecx[ty][n1 + (n2<<4)];
            float xr = bs2f(xs.x), xi = bs2f(xs.y);
            ar += xr*twr - xi*twi; ai += xi*twr + xr*twi;
            rotc(twr, twi, c1, s1);
        }
        short2 pk; pk.x = f2bs(ar); pk.y = f2bs(ai);
        Acx[ty*256 + tid] = pk;
    }
    __syncthreads();
    float a2 = 6.283185307179586f * (float)tid / 256.f;
    float c2v, s2v; __sincosf(a2, &s2v, &c2v);
    size_t plane = (size_t)((br*4 + b)*16 + c) << 16;
    for (int ty = 0; ty < 16; ++ty) {
        float t2r = 1.f, t2i = 0.f, racc = 0.f;
        #pragma unroll
        for (int m = 0; m < 16; ++m) {
            short2 As = Acx[ty*256 + (m<<4) + k1];
            racc += bs2f(As.x)*t2r - bs2f(As.y)*t2i;
            rotc(t2r, t2i, c2v, s2v);
        }
        size_t o = plane + ((size_t)(y0 + ty) << 8) + tid;
        A[o] = f2b(b2f(A[o]) + racc * 0.0625f);
    }
}

// ---------------- fuse 1x1 (48->16), interleaved feat_all out --------------------
__global__ __launch_bounds__(256) void fuse1x1_k(const bf16* __restrict__ fc, const float* __restrict__ wl,
                                                 bf16* __restrict__ feat_all){
    int tid = threadIdx.x, bx = blockIdx.x;
    int pt = bx & 255, b = bx >> 8;
    int p = (pt << 8) + tid;
    float acc[16];
    #pragma unroll
    for (int oc = 0; oc < 16; ++oc) acc[oc] = 0.f;
    for (int ic = 0; ic < 48; ++ic) {
        float v = b2f(fc[((size_t)(b*48 + ic) << 16) + p]);
        #pragma unroll
        for (int oc = 0; oc < 16; ++oc) acc[oc] = fmaf(wl[oc*48 + ic], v, acc[oc]);
    }
    size_t obase = (((size_t)b << 16) + p) << 4;
    #pragma unroll
    for (int h = 0; h < 2; ++h) {
        short8 pk;
        #pragma unroll
        for (int e = 0; e < 8; ++e) pk[e] = f2bs(acc[h*8 + e]);
        *(short8*)&feat_all[obase + h*8] = pk;
    }
}

// ---------------- LIIF MLP via MFMA (center), 256 thr / 64 px, prefetch ----------
__global__ __launch_bounds__(256) void mlp_mfma_k(const short* __restrict__ feat,
        const short* __restrict__ wp,
        const float* __restrict__ b_in, const float* __restrict__ b_h,
        const float* __restrict__ b_out,
        float* __restrict__ fo){
    extern __shared__ short act_s[];   // 64 rows x 264 shorts
    int tid = threadIdx.x, bx = blockIdx.x;
    long P0 = (long)bx * 64;
    for (int idx = tid; idx < 64*160; idx += 256) {
        int pp = idx / 160, j = idx - pp*160;
        long P = P0 + pp;
        int bb = (int)(P >> 16), pim = (int)(P & 65535);
        int s0 = pim >> 8, s1 = pim & 255;
        short v = 0;
        if (j < 144) {
            int iy = j/48, ix = (j>>4)%3, c2 = j&15;
            int yy = s0 + iy - 1, xx = s1 + ix - 1;
            if (yy >= 0 && yy < 256 && xx >= 0 && xx < 256)
                v = feat[((((long)bb << 16) + (yy<<8) + xx) << 4) + c2];
        } else if (j == 146 || j == 147) v = 0x4000;
        act_s[pp*264 + j] = v;
    }
    __syncthreads();

    int l = tid & 63, w = tid >> 6;
    int m_l = l & 15, q = l >> 4;
    int ntb = w*4;
    const short* wph  = wp + 40960;
    const short* wpo  = wp + 40960 + 3*65536;

    float4v acc[4][4];
    short8 bcur[4], bnxt[4];
    #pragma unroll
    for (int mt = 0; mt < 4; ++mt)
        #pragma unroll
        for (int nt = 0; nt < 4; ++nt) acc[mt][nt] = (float4v){0.f,0.f,0.f,0.f};
    {
        const short* bp = wp + ((size_t)ntb*64 + l)*8;
        #pragma unroll
        for (int nt = 0; nt < 4; ++nt) bcur[nt] = *(const short8*)(bp + (size_t)nt*512);
    }
    for (int kt = 0; kt < 5; ++kt) {
        if (kt < 4) {
            const short* bp = wp + ((size_t)((kt+1)*16 + ntb)*64 + l)*8;
            #pragma unroll
            for (int nt = 0; nt < 4; ++nt) bnxt[nt] = *(const short8*)(bp + (size_t)nt*512);
        }
        #pragma unroll
        for (int mt = 0; mt < 4; ++mt) {
            short8 a = *(const short8*)&act_s[(mt*16 + m_l)*264 + kt*32 + q*8];
            #pragma unroll
            for (int nt = 0; nt < 4; ++nt)
                acc[mt][nt] = __builtin_amdgcn_mfma_f32_16x16x32_bf16(a, bcur[nt], acc[mt][nt], 0, 0, 0);
        }
        if (kt < 4) {
            #pragma unroll
            for (int nt = 0; nt < 4; ++nt) bcur[nt] = bnxt[nt];
        }
    }
    __syncthreads();
    #pragma unroll
    for (int nt = 0; nt < 4; ++nt) {
        int n = (ntb + nt)*16 + m_l;
        float bias = b_in[n];
        #pragma unroll
        for (int mt = 0; mt < 4; ++mt)
            #pragma unroll
            for (int r = 0; r < 4; ++r) {
                float vv = fmaxf(acc[mt][nt][r] + bias, 0.f);
                act_s[(mt*16 + q*4 + r)*264 + n] = f2bs(vv);
            }
    }
    __syncthreads();
    for (int L = 0; L < 3; ++L) {
        #pragma unroll
        for (int mt = 0; mt < 4; ++mt)
            #pragma unroll
            for (int nt = 0; nt < 4; ++nt) acc[mt][nt] = (float4v){0.f,0.f,0.f,0.f};
        const short* wl = wph + (size_t)L * 65536;
        {
            const short* bp = wl + ((size_t)ntb*64 + l)*8;
            #pragma unroll
            for (int nt = 0; nt < 4; ++nt) bcur[nt] = *(const short8*)(bp + (size_t)nt*512);
        }
        for (int kt = 0; kt < 8; ++kt) {
            if (kt < 7) {
                const short* bp = wl + ((size_t)((kt+1)*16 + ntb)*64 + l)*8;
                #pragma unroll
                for (int nt = 0; nt < 4; ++nt) bnxt[nt] = *(const short8*)(bp + (size_t)nt*512);
            }
            #pragma unroll
            for (int mt = 0; mt < 4; ++mt) {
                short8 a = *(const short8*)&act_s[(mt*16 + m_l)*264 + kt*32 + q*8];
                #pragma unroll
                for (int nt = 0; nt < 4; ++nt)
                    acc[mt][nt] = __builtin_amdgcn_mfma_f32_16x16x32_bf16(a, bcur[nt], acc[mt][nt], 0, 0, 0);
            }
            if (kt < 7) {
                #pragma unroll
                for (int nt = 0; nt < 4; ++nt) bcur[nt] = bnxt[nt];
            }
        }
        __syncthreads();
        #pragma unroll
        for (int nt = 0; nt < 4; ++nt) {
            int n = (ntb + nt)*16 + m_l;
            float bias = b_h[L*256 + n];
            #pragma unroll
            for (int mt = 0; mt < 4; ++mt)
                #pragma unroll
                for (int r = 0; r < 4; ++r) {
                    float vv = fmaxf(acc[mt][nt][r] + bias, 0.f);
                    act_s[(mt*16 + q*4 + r)*264 + n] = f2bs(vv);
                }
        }
        __syncthreads();
    }
    if (w == 0) {
        float4v o[4];
        #pragma unroll
        for (int mt = 0; mt < 4; ++mt) o[mt] = (float4v){0.f,0.f,0.f,0.f};
        for (int kt = 0; kt < 8; ++kt) {
            short8 bf = *(const short8*)(wpo + ((size_t)kt*64 + l)*8);
            #pragma unroll
            for (int mt = 0; mt < 4; ++mt) {
                short8 a = *(const short8*)&act_s[(mt*16 + m_l)*264 + kt*32 + q*8];
                o[mt] = __builtin_amdgcn_mfma_f32_16x16x32_bf16(a, bf, o[mt], 0, 0, 0);
            }
        }
        float bias = b_out[m_l];
        #pragma unroll
        for (int mt = 0; mt < 4; ++mt) {
            #pragma unroll
            for (int r = 0; r < 4; ++r) {
                long P = P0 + mt*16 + q*4 + r;
                int bb = (int)(P >> 16), pim = (int)(P & 65535);
                int s0 = pim >> 8, s1 = pim & 255;
                float w0 = (s0 == 255 || s1 == 255) ? 0.25f : 1.0f;
                fo[(((long)(bb*16 + m_l)) << 16) + pim] = w0 * (o[mt][r] + bias);
            }
        }
    }
}

// ---------------- LIIF MLP edge corners via MFMA (48 blocks) ---------------------
__global__ __launch_bounds__(256) void mlp_edge_mfma_k(const short* __restrict__ feat,
        const short* __restrict__ wp,
        const float* __restrict__ b_in, const float* __restrict__ b_h,
        const float* __restrict__ b_out,
        float* __restrict__ fo){
    extern __shared__ short act_s[];
    int tid = threadIdx.x, bx = blockIdx.x;
    int E0 = bx * 128;
    for (int idx = tid; idx < 128*160; idx += 256) {
        int pp = idx / 160, j = idx - pp*160;
        int e = E0 + pp; if (e >= 6132) e = 0;
        int bb = e / 1533; int rem = e - bb*1533;
        int cn = rem / 511; int eidx = rem - cn*511;
        int s0 = (eidx < 256) ? 255 : eidx - 256;
        int s1 = (eidx < 256) ? eidx : 255;
        int vx = (cn == 0) ? -1 : 1;
        int vy = (cn == 1) ? -1 : 1;
        int i0 = (vx > 0) ? min(s0+1, 255) : s0;
        int i1 = (vy > 0) ? min(s1+1, 255) : s1;
        short v = 0;
        if (j < 144) {
            int iy = j/48, ix = (j>>4)%3, c2 = j&15;
            int yy = i0 + iy - 1, xx = i1 + ix - 1;
            if (yy >= 0 && yy < 256 && xx >= 0 && xx < 256)
                v = feat[((((long)bb << 16) + (yy<<8) + xx) << 4) + c2];
        } else if (j == 144) v = f2bs(2.f*(float)(s0 - i0));
        else if (j == 145) v = f2bs(2.f*(float)(s1 - i1));
        else if (j >= 146) v = 0x4000;
        act_s[pp*264 + j] = v;
    }
    __syncthreads();

    int l = tid & 63, w = tid >> 6;
    int m_l = l & 15, q = l >> 4;
    int row0 = w * 32;
    const short* wph  = wp + 40960;
    const short* wpo  = wp + 40960 + 3*65536;

    float4v acc[2][16];
    #pragma unroll
    for (int mt = 0; mt < 2; ++mt)
        #pragma unroll
        for (int nt = 0; nt < 16; ++nt) acc[mt][nt] = (float4v){0.f,0.f,0.f,0.f};
    for (int kt = 0; kt < 5; ++kt) {
        short8 a0 = *(const short8*)&act_s[(row0 + m_l)*264 + kt*32 + q*8];
        short8 a1 = *(const short8*)&act_s[(row0 + 16 + m_l)*264 + kt*32 + q*8];
        const short* bp = wp + ((size_t)(kt*16)*64 + l)*8;
        #pragma unroll
        for (int nt = 0; nt < 16; ++nt) {
            short8 bf = *(const short8*)(bp + (size_t)nt*64*8);
            acc[0][nt] = __builtin_amdgcn_mfma_f32_16x16x32_bf16(a0, bf, acc[0][nt], 0, 0, 0);
            acc[1][nt] = __builtin_amdgcn_mfma_f32_16x16x32_bf16(a1, bf, acc[1][nt], 0, 0, 0);
        }
    }
    #pragma unroll
    for (int nt = 0; nt < 16; ++nt) {
        float bias = b_in[nt*16 + m_l];
        #pragma unroll
        for (int mt = 0; mt < 2; ++mt)
            #pragma unroll
            for (int r = 0; r < 4; ++r) {
                float vv = fmaxf(acc[mt][nt][r] + bias, 0.f);
                act_s[(row0 + mt*16 + q*4 + r)*264 + nt*16 + m_l] = f2bs(vv);
            }
    }
    for (int L = 0; L < 3; ++L) {
        #pragma unroll
        for (int mt = 0; mt < 2; ++mt)
            #pragma unroll
            for (int nt = 0; nt < 16; ++nt) acc[mt][nt] = (float4v){0.f,0.f,0.f,0.f};
        const short* wl = wph + (size_t)L * 65536;
        for (int kt = 0; kt < 8; ++kt) {
            short8 a0 = *(const short8*)&act_s[(row0 + m_l)*264 + kt*32 + q*8];
            short8 a1 = *(const short8*)&act_s[(row0 + 16 + m_l)*264 + kt*32 + q*8];
            const short* bp = wl + ((size_t)(kt*16)*64 + l)*8;
            #pragma unroll
            for (int nt = 0; nt < 16; ++nt) {
                short8 bf = *(const short8*)(bp + (size_t)nt*64*8);
                acc[0][nt] = __builtin_amdgcn_mfma_f32_16x16x32_bf16(a0, bf, acc[0][nt], 0, 0, 0);
                acc[1][nt] = __builtin_amdgcn_mfma_f32_16x16x32_bf16(a1, bf, acc[1][nt], 0, 0, 0);
            }
        }
        #pragma unroll
        for (int nt = 0; nt < 16; ++nt) {
            float bias = b_h[L*256 + nt*16 + m_l];
            #pragma unroll
            for (int mt = 0; mt < 2; ++mt)
                #pragma unroll
                for (int r = 0; r < 4; ++r) {
                    float vv = fmaxf(acc[mt][nt][r] + bias, 0.f);
                    act_s[(row0 + mt*16 + q*4 + r)*264 + nt*16 + m_l] = f2bs(vv);
                }
        }
    }
    float4v o0 = (float4v){0.f,0.f,0.f,0.f}, o1 = (float4v){0.f,0.f,0.f,0.f};
    for (int kt = 0; kt < 8; ++kt) {
        short8 a0 = *(const short8*)&act_s[(row0 + m_l)*264 + kt*32 + q*8];
        short8 a1 = *(const short8*)&act_s[(row0 + 16 + m_l)*264 + kt*32 + q*8];
        short8 bf = *(const short8*)(wpo + ((size_t)kt*64 + l)*8);
        o0 = __builtin_amdgcn_mfma_f32_16x16x32_bf16(a0, bf, o0, 0, 0, 0);
        o1 = __builtin_amdgcn_mfma_f32_16x16x32_bf16(a1, bf, o1, 0, 0, 0);
    }
    float bias = b_out[m_l];
    #pragma unroll
    for (int mt = 0; mt < 2; ++mt) {
        float4v* op = mt ? &o1 : &o0;
        #pragma unroll
        for (int r = 0; r < 4; ++r) {
            int e = E0 + row0 + mt*16 + q*4 + r;
            float scale = (e < 6132) ? 0.25f : 0.f;
            if (e >= 6132) e = 0;
            int bb = e / 1533; int rem = e - bb*1533;
            int cn = rem / 511; int eidx = rem - cn*511;
            int s0 = (eidx < 256) ? 255 : eidx - 256;
            int s1 = (eidx < 256) ? eidx : 255;
            atomicAdd(&fo[(((long)(bb*16 + m_l)) << 16) + (s0<<8) + s1],
                      scale * ((*op)[r] + bias));
        }
    }
}

// ---------------- final conv (16->4) + lrms_up -----------------------------------
__global__ __launch_bounds__(256) void final_k(const float* __restrict__ fo, const float* __restrict__ w,
                                               const float* __restrict__ lrms_up, float* __restrict__ out){
    int tid = threadIdx.x, bx = blockIdx.x;
    int y = bx & 255, oc = (bx >> 8) & 3, b = bx >> 10;
    int x = tid;
    const float* wg = w + (size_t)oc * 144;
    float acc = 0.f;
    for (int ic = 0; ic < 16; ++ic) {
        const float* base = fo + (((size_t)(b*16 + ic)) << 16);
        #pragma unroll
        for (int ky = 0; ky < 3; ++ky) {
            int yy = y + ky - 1; if (yy < 0 || yy > 255) continue;
            const float* rowp = base + (yy<<8);
            float v0 = (x > 0)   ? rowp[x-1] : 0.f;
            float v1 = rowp[x];
            float v2 = (x < 255) ? rowp[x+1] : 0.f;
            const float* wr = wg + ic*9 + ky*3;
            acc = fmaf(wr[0], v0, fmaf(wr[1], v1, fmaf(wr[2], v2, acc)));
        }
    }
    size_t oidx = (((size_t)(b*4 + oc)) << 16) + (y<<8) + x;
    out[oidx] = acc + lrms_up[oidx];
}

// ================================================================================
extern "C" void kernel_launch(void* const* d_in, const int* in_sizes, int n_in,
                              void* d_out, int out_size, void* d_ws, size_t ws_size,
                              hipStream_t stream) {
    const float* lrms     = (const float*)d_in[0];
    const float* pan      = (const float*)d_in[1];
    const float* w_convps = (const float*)d_in[2];
    const float* hor_w1   = (const float*)d_in[3];
    const float* hor_w2   = (const float*)d_in[4];
    const float* ffc_l2l  = (const float*)d_in[5];
    const float* ffc_l2g  = (const float*)d_in[6];
    const float* ffc_g2l  = (const float*)d_in[7];
    const float* ffc_spec = (const float*)d_in[8];
    const float* ref_in   = (const float*)d_in[9];
    const float* ref_b1   = (const float*)d_in[10];
    const float* ref_b2   = (const float*)d_in[11];
    const float* ref_ca1  = (const float*)d_in[12];
    const float* ref_ca2  = (const float*)d_in[13];
    const float* ref_out  = (const float*)d_in[14];
    const float* w_fuse   = (const float*)d_in[15];
    const float* w_liif   = (const float*)d_in[16];
    const float* w_hp     = (const float*)d_in[17];
    const float* mw_in    = (const float*)d_in[18];
    const float* mb_in    = (const float*)d_in[19];
    const float* mw_h     = (const float*)d_in[20];
    const float* mb_h     = (const float*)d_in[21];
    const float* mw_out   = (const float*)d_in[22];
    const float* mb_out   = (const float*)d_in[23];
    float* out = (float*)d_out;

    const size_t PLANE = 65536;
    char* base = (char*)d_ws;
    size_t off = 0;
    auto alloc = [&](size_t bytes){ void* p = base + off; off += (bytes + 255) & ~(size_t)255; return p; };
    float* lrms_up  = (float*)alloc(16*PLANE*4);
    bf16*  feat2    = (bf16*) alloc(24*PLANE*2);
    bf16*  bA       = (bf16*) alloc(192*PLANE*2);
    bf16*  bB       = (bf16*) alloc(192*PLANE*2);
    bf16*  bC       = (bf16*) alloc(192*PLANE*2);
    bf16*  bF       = (bf16*) alloc(192*PLANE*2);
    bf16*  fusedCat = (bf16*) alloc(192*PLANE*2);
    bf16*  feat_all = (bf16*) alloc(64*PLANE*2);
    float* fo       = (float*)alloc(64*PLANE*4);
    const size_t FFTB = (size_t)3*4*8*256*129;
    bf16* re0 = (bf16*)alloc(FFTB*2); bf16* im0 = (bf16*)alloc(FFTB*2);
    bf16* re1 = (bf16*)alloc(FFTB*2); bf16* im1 = (bf16*)alloc(FFTB*2);
    short* wpack = (short*)alloc(241664*2);
    short* wconv = (short*)alloc(45*2560*2);
    float* means3 = (float*)alloc(3*192*4);
    if (off > ws_size) return;

    hipMemsetAsync(means3, 0, 3*192*4, stream);
    init_k<<<dim3(4096 + 1395), dim3(256), 0, stream>>>(lrms, w_convps, lrms_up,
        mw_in, mw_h, mw_out, hor_w2, ref_in, ref_b1, ref_b2, ref_out,
        ffc_l2l, ffc_l2g, ffc_g2l, wpack, wconv);

    GK3 g3;
    {
        const int kss[3] = {5, 27, 41};
        const double sgs[3] = {1.5, 2.0, 2.8};
        for (int br = 0; br < 3; ++br) {
            g3.ks[br] = kss[br];
            double tmp[41]; double s = 0.0; double c = (kss[br]-1)/2.0;
            for (int i = 0; i < kss[br]; ++i) { double d = i - c; tmp[i] = exp(-(d*d)/(2.0*sgs[br]*sgs[br])); s += tmp[i]; }
            for (int i = 0; i < 41; ++i) g3.k[br][i] = (i < kss[br]) ? (float)(tmp[i]/s) : 0.f;
        }
    }
    gauss_hp_k<<<dim3(6144), dim3(256), 0, stream>>>(pan, lrms_up, feat2, g3);

    // hornet
    convA_k<<<dim3(3072), dim3(256), 0, stream>>>(feat2, 2, 2, hor_w1, 720, 45, bA, ACT_GELU);
    convM_k<<<dim3(768), dim3(256), 0, stream>>>(bA, wconv + 0*3*2560, bB, ACT_NONE, nullptr);

    for (int step = 0; step < 3; ++step) {
        bf16* Xin = (step == 0) ? bB : bA;
        bf16* Yb  = (step == 0) ? bA : bB;
        bf16* Db  = (step == 0) ? bB : bA;
        convM_k<<<dim3(768), dim3(256), 0, stream>>>(Xin, wconv + (1+step)*3*2560, Yb, ACT_NONE, nullptr);
        convM_k<<<dim3(768), dim3(256), 0, stream>>>(Yb,  wconv + (4+step)*3*2560, bC, ACT_RELU, nullptr);
        convM_k<<<dim3(768), dim3(256), 0, stream>>>(bC,  wconv + (7+step)*3*2560, Db, ACT_NONE, means3 + step*192);
        convOutM_k<<<dim3(768), dim3(256), 0, stream>>>(Yb, Db, means3 + step*192, ref_ca1, ref_ca2,
                                                        wconv + (12+step)*3*2560, w_fuse, step, bF, fusedCat);
        if (step < 2) {
            convM_k<<<dim3(768), dim3(256), 0, stream>>>(bF, wconv + (10+step)*3*2560, bA, ACT_NONE, nullptr);
            rfft_wT_k<<<dim3(1536), dim3(256), 0, stream>>>(bF, re0, im0);
            fftspec_hT_k<<<dim3(1548), dim3(256), 0, stream>>>(re0, im0, ffc_spec, step, re1, im1);
            irfft_wT_k<<<dim3(1536), dim3(256), 0, stream>>>(re1, im1, bA);
        }
    }

    fuse1x1_k<<<dim3(1024), dim3(256), 0, stream>>>(fusedCat, w_liif, feat_all);
    mlp_mfma_k<<<dim3(4096), dim3(256), 64*264*2, stream>>>((const short*)feat_all, wpack, mb_in, mb_h, mb_out, fo);
    mlp_edge_mfma_k<<<dim3(48), dim3(256), 128*264*2, stream>>>((const short*)feat_all, wpack, mb_in, mb_h, mb_out, fo);
    final_k<<<dim3(4096), dim3(256), 0, stream>>>(fo, w_hp, lrms_up, out);
}